// Round 4
// baseline (584.441 us; speedup 1.0000x reference)
//
#include <hip/hip_runtime.h>
#include <math.h>

// ---------- types ----------
typedef __bf16 bf16_t;
typedef __bf16 bf16x8 __attribute__((ext_vector_type(8)));
typedef __bf16 bf16x4 __attribute__((ext_vector_type(4)));
typedef float  f32x4  __attribute__((ext_vector_type(4)));

#define MFMA16(a, b, c) __builtin_amdgcn_mfma_f32_16x16x32_bf16((a), (b), (c), 0, 0, 0)

// B=2, N=M=2048, QUERY_DIM=CONTEXT_DIM=1024, HEADS=8, DIM_HEAD=64, INNER=512
#define INNER   512
#define DHEAD   64
// SCALE * log2(e): Q pre-scaled so softmax runs in exp2 domain
#define QSCALE  0.18033688f
#define NBLK    512u

// direct HBM -> LDS, 16 B per lane; LDS dest = wave-uniform base + lane*16
__device__ __forceinline__ void g2l(const bf16_t* g, bf16_t* l) {
  __builtin_amdgcn_global_load_lds(
      (const __attribute__((address_space(1))) unsigned int*)g,
      (__attribute__((address_space(3))) unsigned int*)l, 16, 0, 0);
}

// ---------- device-scope grid barrier ----------
// bar is zeroed by hipMemsetAsync before every launch (workspace is re-poisoned,
// NOT zeroed, between harness iterations -- round-3 deadlock). Monotonic counter
// with explicit phase goal: after phase p's barrier, bar == p*NBLK.
__device__ __forceinline__ void gridbar(unsigned int* bar, unsigned int phase) {
  __threadfence();                       // release: agent-scope writeback
  __syncthreads();
  if (threadIdx.x == 0) {
    __hip_atomic_fetch_add(bar, 1u, __ATOMIC_ACQ_REL, __HIP_MEMORY_SCOPE_AGENT);
    const unsigned int goal = phase * NBLK;
    while (__hip_atomic_load(bar, __ATOMIC_ACQUIRE,
                             __HIP_MEMORY_SCOPE_AGENT) < goal) {
      __builtin_amdgcn_s_sleep(2);
    }
  }
  __syncthreads();
  __threadfence();                       // acquire: invalidate caches
}

// ---------- stage 0: weight transpose+convert (512 tiles exactly) ----------
__device__ __forceinline__ void pre_w_stage(int t, bf16_t* sm,
                                            const float* __restrict__ Wq,
                                            const float* __restrict__ Wk,
                                            const float* __restrict__ Wv,
                                            const float* __restrict__ Wo,
                                            bf16_t* __restrict__ WqT,
                                            bf16_t* __restrict__ WkT,
                                            bf16_t* __restrict__ WvT,
                                            bf16_t* __restrict__ WoT) {
  float* tile = (float*)sm;          // [64][65] = 16.6 KB of the 65 KB smem
  int z = t >> 7, bid = t & 127;
  const float* W; bf16_t* WT; int K, N;
  if (z == 0)      { W = Wq; WT = WqT; K = 1024; N = 512; }
  else if (z == 1) { W = Wk; WT = WkT; K = 1024; N = 512; }
  else if (z == 2) { W = Wv; WT = WvT; K = 1024; N = 512; }
  else             { W = Wo; WT = WoT; K = 512;  N = 1024; }
  int tK = K >> 6;
  int kt = bid % tK, nt = bid / tK;
  int k0 = kt << 6, n0 = nt << 6;
  for (int idx = threadIdx.x; idx < 4096; idx += 256) {
    int r = idx >> 6, c = idx & 63;
    tile[r * 65 + c] = W[(size_t)(k0 + r) * N + n0 + c];
  }
  __syncthreads();
  for (int idx = threadIdx.x; idx < 4096; idx += 256) {
    int r = idx >> 6, c = idx & 63;
    WT[(size_t)(n0 + r) * K + k0 + c] = (bf16_t)tile[c * 65 + r];
  }
}

// ---------- BMx128 GEMM core, BK=64, double-buffered staging, early issue ----------
// LDS: As = sm[0 .. 2*BM*64), Bs = sm[2*BM*64 .. 2*BM*64 + 2*128*64)
// B operand: global_load_lds from pre-swizzled global address (bf16).
// A operand: if AF32, reg-staged from fp32 (issue-early / cvt+ds_write-late),
//            swizzled ds_write_b128; else g2l like B.
// phys chunk = logical chunk ^ (row&7) within each 128-B row.
// mode 0: bf16 out * scale; mode 1: f32 out + bias; mode 2: scatter to Vt.
template<int BM, bool AF32>
__device__ __forceinline__ void gemm_core(bf16_t* sm,
                                          const void* __restrict__ Ap,
                                          const bf16_t* __restrict__ Bt,
                                          int K, int N, int row0, int n0,
                                          int mode, float scale,
                                          bf16_t* __restrict__ Cb,
                                          float* __restrict__ Cf,
                                          const float* __restrict__ bias) {
  constexpr int MI = BM / 32;              // A frag-rows per wave == A staging steps
  bf16_t* As = sm;                         // 2*BM*64 elems
  bf16_t* Bs = sm + 2 * BM * 64;           // 2*128*64 elems
  const int tid = threadIdx.x;
  const int w = tid >> 6, lane = tid & 63, quad = lane >> 4, l16 = lane & 15;

  const int sr8  = lane >> 3;                    // 0..7
  const int slog = ((lane & 7) ^ sr8) << 3;      // logical col (elems)
  const float*  gaF = nullptr;
  const bf16_t* gaB = nullptr;
  {
    size_t aoff = (size_t)(row0 + w * (BM / 4) + sr8) * K + slog;
    if constexpr (AF32) gaF = (const float*)Ap + aoff;
    else                gaB = (const bf16_t*)Ap + aoff;
  }
  const bf16_t* gb = Bt + (size_t)(n0 + w * 32 + sr8) * K + slog;
  bf16_t* lA = As + w * (BM / 4) * 64;           // + buf*BM*64 + p*512
  bf16_t* lB = Bs + w * 2048;                    // + buf*8192  + p*512

  f32x4 acc[MI][4];
#pragma unroll
  for (int i = 0; i < MI; ++i)
#pragma unroll
    for (int j = 0; j < 4; ++j) acc[i][j] = f32x4{0.f, 0.f, 0.f, 0.f};

  const int mrow = (w & 1) * (BM / 2), ncol = (w >> 1) << 6;
  const int KT = K >> 6;

  // prologue: tile 0 -> buf 0
  if constexpr (AF32) {
#pragma unroll
    for (int p = 0; p < MI; ++p) {
      const float* s = gaF + (size_t)(p * 8) * K;
      f32x4 f0 = *(const f32x4*)s;
      f32x4 f1 = *(const f32x4*)(s + 4);
      bf16x8 h;
#pragma unroll
      for (int e = 0; e < 4; ++e) { h[e] = (bf16_t)f0[e]; h[4 + e] = (bf16_t)f1[e]; }
      *(bf16x8*)&lA[p * 512 + lane * 8] = h;
    }
  } else {
#pragma unroll
    for (int p = 0; p < MI; ++p)
      g2l(gaB + (size_t)(p * 8) * K, lA + p * 512);
  }
#pragma unroll
  for (int p = 0; p < 4; ++p)
    g2l(gb + (size_t)(p * 8) * K, lB + p * 512);

  for (int kc = 0; kc < KT; ++kc) {
    const int curA = (kc & 1) * (BM * 64), nxtA = ((kc + 1) & 1) * (BM * 64);
    const int curB = (kc & 1) * 8192,      nxtB = ((kc + 1) & 1) * 8192;
    __syncthreads();              // drains tile-kc loads/writes; publishes buf[cur]
    f32x4 fpre[2 * MI];
    const bool pf = (kc + 1 < KT);
    if (pf) {                     // issue tile kc+1 early; MFMA hides flight
      const int k0 = (kc + 1) * 64;
#pragma unroll
      for (int p = 0; p < 4; ++p)
        g2l(gb + (size_t)(p * 8) * K + k0, lB + nxtB + p * 512);
      if constexpr (AF32) {
#pragma unroll
        for (int p = 0; p < MI; ++p) {
          const float* s = gaF + (size_t)(p * 8) * K + k0;
          fpre[2 * p]     = *(const f32x4*)s;
          fpre[2 * p + 1] = *(const f32x4*)(s + 4);
        }
      } else {
#pragma unroll
        for (int p = 0; p < MI; ++p)
          g2l(gaB + (size_t)(p * 8) * K + k0, lA + nxtA + p * 512);
      }
    }
#pragma unroll
    for (int ks = 0; ks < 2; ++ks) {
      const int phys = ((ks * 4 + quad) ^ (l16 & 7)) << 3;
      bf16x8 af[MI], bfr[4];
#pragma unroll
      for (int i = 0; i < MI; ++i)
        af[i] = *(const bf16x8*)&As[curA + (mrow + i * 16 + l16) * 64 + phys];
#pragma unroll
      for (int j = 0; j < 4; ++j)
        bfr[j] = *(const bf16x8*)&Bs[curB + (ncol + j * 16 + l16) * 64 + phys];
#pragma unroll
      for (int i = 0; i < MI; ++i)
#pragma unroll
        for (int j = 0; j < 4; ++j)
          acc[i][j] = MFMA16(af[i], bfr[j], acc[i][j]);
    }
    if (pf) {
      if constexpr (AF32) {       // write-late: cvt + swizzled ds_write into nxt
#pragma unroll
        for (int p = 0; p < MI; ++p) {
          bf16x8 h;
#pragma unroll
          for (int e = 0; e < 4; ++e) {
            h[e]     = (bf16_t)fpre[2 * p][e];
            h[4 + e] = (bf16_t)fpre[2 * p + 1][e];
          }
          *(bf16x8*)&lA[nxtA + p * 512 + lane * 8] = h;
        }
      }
    }
  }

  // epilogue: C/D layout col=l16, row=quad*4+reg
#pragma unroll
  for (int i = 0; i < MI; ++i) {
    int row = row0 + mrow + i * 16 + quad * 4;
#pragma unroll
    for (int j = 0; j < 4; ++j) {
      int col = n0 + ncol + j * 16 + l16;
      if (mode == 2) {
        // scatter to Vt[bh=b*8+h][d][key]: row -> (b,key), col -> (h,d)
        int bb = row >> 11, key = row & 2047;
        int hh = col >> 6,  d   = col & 63;
        bf16x4 v = { (bf16_t)acc[i][j][0], (bf16_t)acc[i][j][1],
                     (bf16_t)acc[i][j][2], (bf16_t)acc[i][j][3] };
        *(bf16x4*)&Cb[((size_t)((bb * 8 + hh) * 64 + d)) * 2048 + key] = v;
      } else {
#pragma unroll
        for (int r = 0; r < 4; ++r) {
          if (mode == 1) Cf[(size_t)(row + r) * N + col] = acc[i][j][r] + bias[col];
          else           Cb[(size_t)(row + r) * N + col] = (bf16_t)(acc[i][j][r] * scale);
        }
      }
    }
  }
}

// ---------- stage 2: flash attention (512 tiles exactly) ----------
// smem: Ks = sm[0..16384)  Vs = sm[16384..24576)  Ps = sm[24576..33280)
__device__ __forceinline__ void attn_stage(int bid, bf16_t* sm,
                                           const bf16_t* __restrict__ Qb,
                                           const bf16_t* __restrict__ Kb,
                                           const bf16_t* __restrict__ Vt,
                                           bf16_t* __restrict__ AO) {
  bf16_t* Ks = sm;                 // [buf][key][d] rows 128 B, swizzle r&7
  bf16_t* Vs = sm + 16384;         // [d][key]      rows 256 B, swizzle r&15
  bf16_t* Ps = sm + 24576;         // [q][key]      padded, wave-private rows

  const int tid = threadIdx.x;
  const int w = tid >> 6, lane = tid & 63, quad = lane >> 4, l16 = lane & 15;
  const int qt = bid & 31;          // 0..31
  const int bh = bid >> 5;          // 0..15
  const int b = bh >> 3, h = bh & 7;

  const int qrow = b * 2048 + qt * 64 + w * 16 + l16;
  const bf16_t* qptr = Qb + (size_t)qrow * INNER + h * DHEAD;
  bf16x8 bq[2];
  bq[0] = *(const bf16x8*)(qptr + quad * 8);
  bq[1] = *(const bf16x8*)(qptr + 32 + quad * 8);

  f32x4 o[4];
#pragma unroll
  for (int dt = 0; dt < 4; ++dt) o[dt] = f32x4{0.f, 0.f, 0.f, 0.f};
  float m_s = -__builtin_inff(), l_s = 0.f;

  const bf16_t* kbase  = Kb + ((size_t)b * 2048) * INNER + h * DHEAD;
  const bf16_t* vtbase = Vt + ((size_t)bh * 64) * 2048;

  const int krow = lane >> 3;
  const int kcol = ((lane & 7) ^ (lane >> 3)) << 3;
  const int vrow = lane >> 4;

#pragma unroll
  for (int p = 0; p < 4; ++p)
    g2l(kbase + (size_t)(w * 32 + p * 8 + krow) * INNER + kcol,
        &Ks[w * 2048 + p * 512]);

  for (int kt = 0; kt < 16; ++kt) {
    const int cur = (kt & 1) * 8192, nxt = ((kt + 1) & 1) * 8192;
    __syncthreads();
    if (kt < 16 - 1) {
#pragma unroll
      for (int p = 0; p < 4; ++p)
        g2l(kbase + (size_t)((kt + 1) * 128 + w * 32 + p * 8 + krow) * INNER + kcol,
            &Ks[nxt + w * 2048 + p * 512]);
    }
#pragma unroll
    for (int p = 0; p < 4; ++p) {
      int vlog = ((lane & 15) ^ ((p * 4 + vrow) & 15)) << 3;
      g2l(vtbase + (size_t)(w * 16 + p * 4 + vrow) * 2048 + kt * 128 + vlog,
          &Vs[w * 2048 + p * 512]);
    }

    f32x4 s[8];
#pragma unroll
    for (int jt = 0; jt < 8; ++jt) s[jt] = f32x4{0.f, 0.f, 0.f, 0.f};
#pragma unroll
    for (int jt = 0; jt < 8; ++jt) {
#pragma unroll
      for (int ks = 0; ks < 2; ++ks) {
        int phys = ((ks * 4 + quad) ^ (l16 & 7)) << 3;
        bf16x8 ak = *(const bf16x8*)&Ks[cur + (jt * 16 + l16) * 64 + phys];
        s[jt] = MFMA16(ak, bq[ks], s[jt]);
      }
    }

    float mx = -__builtin_inff();
#pragma unroll
    for (int jt = 0; jt < 8; ++jt) {
      float a = fmaxf(fmaxf(s[jt][0], s[jt][1]), fmaxf(s[jt][2], s[jt][3]));
      mx = fmaxf(mx, a);
    }
    mx = fmaxf(mx, __shfl_xor(mx, 16, 64));
    mx = fmaxf(mx, __shfl_xor(mx, 32, 64));
    float mnew = fmaxf(m_s, mx);
    float alpha = __builtin_amdgcn_exp2f(m_s - mnew);
    float rs = 0.f;
#pragma unroll
    for (int jt = 0; jt < 8; ++jt) {
#pragma unroll
      for (int r = 0; r < 4; ++r) {
        float p = __builtin_amdgcn_exp2f(s[jt][r] - mnew);
        s[jt][r] = p;
        rs += p;
      }
    }
    rs += __shfl_xor(rs, 16, 64);
    rs += __shfl_xor(rs, 32, 64);
    l_s = l_s * alpha + rs;
    m_s = mnew;
#pragma unroll
    for (int dt = 0; dt < 4; ++dt) o[dt] *= alpha;

#pragma unroll
    for (int jt = 0; jt < 8; ++jt) {
      bf16x4 pk = { (bf16_t)s[jt][0], (bf16_t)s[jt][1],
                    (bf16_t)s[jt][2], (bf16_t)s[jt][3] };
      *(bf16x4*)&Ps[(w * 16 + l16) * 136 + jt * 16 + quad * 4] = pk;
    }

    __syncthreads();

#pragma unroll
    for (int kc = 0; kc < 4; ++kc) {
      bf16x8 bp = *(const bf16x8*)&Ps[(w * 16 + l16) * 136 + kc * 32 + quad * 8];
#pragma unroll
      for (int dt = 0; dt < 4; ++dt) {
        int phys = ((kc * 4 + quad) ^ l16) << 3;
        bf16x8 av = *(const bf16x8*)&Vs[(dt * 16 + l16) * 128 + phys];
        o[dt] = MFMA16(av, bp, o[dt]);
      }
    }
  }

  float inv = 1.0f / l_s;
#pragma unroll
  for (int dt = 0; dt < 4; ++dt) {
    bf16x4 ov = { (bf16_t)(o[dt][0] * inv), (bf16_t)(o[dt][1] * inv),
                  (bf16_t)(o[dt][2] * inv), (bf16_t)(o[dt][3] * inv) };
    *(bf16x4*)&Ps[(w * 16 + l16) * 136 + dt * 16 + quad * 4] = ov;
  }
  __syncthreads();
  {
    int sr = tid >> 2, sc = (tid & 3) << 4;
    int4 r0 = *(const int4*)&Ps[sr * 136 + sc];
    int4 r1 = *(const int4*)&Ps[sr * 136 + sc + 8];
    bf16_t* aout = AO + ((size_t)(b * 2048 + qt * 64 + sr)) * INNER + h * DHEAD + sc;
    *(int4*)aout       = r0;
    *(int4*)(aout + 8) = r1;
  }
}

// ---------- fused persistent kernel (plain launch, manual co-residency) ----------
// 512 blocks x 256 threads, 66560 B LDS, __launch_bounds__(256,2) -> exactly
// 2 blocks/CU x 256 CUs = 512 co-resident blocks. Stage grids all tile 512:
//   s0 pre_w: 4 matrices x 128 tiles = 512
//   s1 qkv:   Q 128 (BM=128) + K 128 (BM=128) + V 256 (BM=64) = 512
//   s2 attn:  32 qt x 16 bh = 512
//   s3 out:   64 M-tiles (BM=64) x 8 N-tiles = 512
__global__ __launch_bounds__(256, 2) void fused_k(
    const float* __restrict__ x,   const float* __restrict__ ctx,
    const float* __restrict__ Wq,  const float* __restrict__ Wk,
    const float* __restrict__ Wv,  const float* __restrict__ Wo,
    const float* __restrict__ bo,
    bf16_t* __restrict__ WqT, bf16_t* __restrict__ WkT,
    bf16_t* __restrict__ WvT, bf16_t* __restrict__ WoT,
    bf16_t* __restrict__ Qb,  bf16_t* __restrict__ Kb,
    bf16_t* __restrict__ Vt,  bf16_t* __restrict__ AO,
    float* __restrict__ out,  unsigned int* bar) {
  __shared__ __align__(16) bf16_t smem[33280];   // 66560 B
  const int bid = blockIdx.x;

  // stage 0: weight transpose+convert
  pre_w_stage(bid, smem, Wq, Wk, Wv, Wo, WqT, WkT, WvT, WoT);
  gridbar(bar, 1u);

  // stage 1: QKV projections (A = fp32 x/ctx, fused convert)
  if (bid < 128) {
    gemm_core<128, true>(smem, x, WqT, 1024, 512, (bid >> 2) * 128, (bid & 3) * 128,
                         0, QSCALE, Qb, nullptr, nullptr);
  } else if (bid < 256) {
    int t = bid - 128;
    gemm_core<128, true>(smem, ctx, WkT, 1024, 512, (t >> 2) * 128, (t & 3) * 128,
                         0, 1.0f, Kb, nullptr, nullptr);
  } else {
    int t = bid - 256;
    gemm_core<64, true>(smem, ctx, WvT, 1024, 512, (t >> 2) * 64, (t & 3) * 128,
                        2, 1.0f, Vt, nullptr, nullptr);
  }
  gridbar(bar, 2u);

  // stage 2: flash attention
  attn_stage(bid, smem, Qb, Kb, Vt, AO);
  gridbar(bar, 3u);

  // stage 3: output projection + bias
  gemm_core<64, false>(smem, AO, WoT, 512, 1024, (bid >> 3) * 64, (bid & 7) * 128,
                       1, 1.0f, nullptr, out, bo);
}

// ---------- launch ----------
extern "C" void kernel_launch(void* const* d_in, const int* in_sizes, int n_in,
                              void* d_out, int out_size, void* d_ws, size_t ws_size,
                              hipStream_t stream) {
  const float* x   = (const float*)d_in[0];
  const float* ctx = (const float*)d_in[1];
  const float* Wq  = (const float*)d_in[2];
  const float* Wk  = (const float*)d_in[3];
  const float* Wv  = (const float*)d_in[4];
  const float* Wo  = (const float*)d_in[5];
  const float* bo  = (const float*)d_in[6];
  float* out = (float*)d_out;

  char* ws = (char*)d_ws;
  const size_t MB = 1048576;
  bf16_t* WqT = (bf16_t*)(ws + 0 * MB);    //  1 MB  [512][1024]
  bf16_t* WkT = (bf16_t*)(ws + 1 * MB);    //  1 MB
  bf16_t* WvT = (bf16_t*)(ws + 2 * MB);    //  1 MB
  bf16_t* WoT = (bf16_t*)(ws + 3 * MB);    //  1 MB  [1024][512]
  bf16_t* Qb  = (bf16_t*)(ws + 4 * MB);    //  4 MB  [4096][512] (pre-scaled)
  bf16_t* Kb  = (bf16_t*)(ws + 8 * MB);    //  4 MB  [4096][512]
  bf16_t* Vt  = (bf16_t*)(ws + 12 * MB);   //  4 MB  [16][64][2048]
  bf16_t* AO  = (bf16_t*)(ws + 16 * MB);   //  4 MB  [4096][512]
  unsigned int* bar = (unsigned int*)(ws + 20 * MB);

  // workspace is re-poisoned (not zeroed) between iterations: barrier counter
  // MUST be explicitly zeroed each launch (round-3 deadlock otherwise).
  hipMemsetAsync((void*)bar, 0, 64, stream);

  fused_k<<<dim3(512), dim3(256), 0, stream>>>(
      x, ctx, Wq, Wk, Wv, Wo, bo,
      WqT, WkT, WvT, WoT, Qb, Kb, Vt, AO, out, bar);
}

// Round 5
// 259.860 us; speedup vs baseline: 2.2491x; 2.2491x over previous
//
#include <hip/hip_runtime.h>
#include <math.h>

// ---------- types ----------
typedef __bf16 bf16_t;
typedef __bf16 bf16x8 __attribute__((ext_vector_type(8)));
typedef __bf16 bf16x4 __attribute__((ext_vector_type(4)));
typedef float  f32x4  __attribute__((ext_vector_type(4)));

#define MFMA16(a, b, c) __builtin_amdgcn_mfma_f32_16x16x32_bf16((a), (b), (c), 0, 0, 0)

// B=2, N=M=2048, QUERY_DIM=CONTEXT_DIM=1024, HEADS=8, DIM_HEAD=64, INNER=512
#define INNER   512
#define DHEAD   64
// SCALE * log2(e): Q pre-scaled so softmax runs in exp2 domain
#define QSCALE  0.18033688f
#define NBLK    512u
#define NXCD    8u

// direct HBM -> LDS, 16 B per lane; LDS dest = wave-uniform base + lane*16
__device__ __forceinline__ void g2l(const bf16_t* g, bf16_t* l) {
  __builtin_amdgcn_global_load_lds(
      (const __attribute__((address_space(1))) unsigned int*)g,
      (__attribute__((address_space(3))) unsigned int*)l, 16, 0, 0);
}

// ---------- device-scope grid barrier, minimal-coherence version ----------
// Round-4 lesson: __threadfence + ACQUIRE spin = whole-L2 wbl2/inv per block per
// spin iteration -> ~400us of fence serialization. This version:
//   * relaxed atomics only (no cache side effects on spins)
//   * exactly ONE buffer_wbl2 sc1 per XCD per barrier (elected via CAS on
//     elect[XCC_ID]); 8 concurrent writebacks flush all dirty intermediate data
//     to the shared L3.
//   * NO invalidates: every intermediate buffer is written once, then read by
//     blocks whose caches never touched those addresses (write-once/read-once
//     dataflow) -> no stale copies can exist.
// Layout in bar[]: [0]=arrive, [16]=done, [32+x*16]=elect[x] (all zeroed at launch).
// Deadlock audit: 512 blocks at exactly 2/CU fill all 256 CUs -> every XCD hosts
// blocks -> exactly 8 CAS winners/phase; arrive hits 512p, done hits 8p.
__device__ __forceinline__ void gridbar(unsigned int* bar, unsigned int phase) {
  asm volatile("s_waitcnt vmcnt(0) lgkmcnt(0)" ::: "memory"); // my wave's stores in L2
  __syncthreads();   // compiler also drains all waves' vmem before s_barrier
  if (threadIdx.x == 0) {
    unsigned int xcd;
    asm volatile("s_getreg_b32 %0, hwreg(HW_REG_XCC_ID)" : "=s"(xcd));
    xcd &= (NXCD - 1u);
    unsigned int exp = phase - 1u;
    bool flusher = __hip_atomic_compare_exchange_strong(
        &bar[32 + xcd * 16], &exp, phase,
        __ATOMIC_RELAXED, __ATOMIC_RELAXED, __HIP_MEMORY_SCOPE_AGENT);
    __hip_atomic_fetch_add(&bar[0], 1u, __ATOMIC_RELAXED,
                           __HIP_MEMORY_SCOPE_AGENT);
    if (flusher) {
      while (__hip_atomic_load(&bar[0], __ATOMIC_RELAXED,
                               __HIP_MEMORY_SCOPE_AGENT) < phase * NBLK)
        __builtin_amdgcn_s_sleep(1);
      asm volatile("buffer_wbl2 sc1" ::: "memory");      // flush my XCD's L2 -> L3
      asm volatile("s_waitcnt vmcnt(0)" ::: "memory");   // wbl2 completion
      __hip_atomic_fetch_add(&bar[16], 1u, __ATOMIC_RELAXED,
                             __HIP_MEMORY_SCOPE_AGENT);
    }
    while (__hip_atomic_load(&bar[16], __ATOMIC_RELAXED,
                             __HIP_MEMORY_SCOPE_AGENT) < phase * NXCD)
      __builtin_amdgcn_s_sleep(1);
  }
  __syncthreads();
}

// ---------- stage 0: weight transpose+convert (512 tiles exactly) ----------
__device__ __forceinline__ void pre_w_stage(int t, bf16_t* sm,
                                            const float* __restrict__ Wq,
                                            const float* __restrict__ Wk,
                                            const float* __restrict__ Wv,
                                            const float* __restrict__ Wo,
                                            bf16_t* __restrict__ WqT,
                                            bf16_t* __restrict__ WkT,
                                            bf16_t* __restrict__ WvT,
                                            bf16_t* __restrict__ WoT) {
  float* tile = (float*)sm;          // [64][65] = 16.6 KB of the 65 KB smem
  int z = t >> 7, bid = t & 127;
  const float* W; bf16_t* WT; int K, N;
  if (z == 0)      { W = Wq; WT = WqT; K = 1024; N = 512; }
  else if (z == 1) { W = Wk; WT = WkT; K = 1024; N = 512; }
  else if (z == 2) { W = Wv; WT = WvT; K = 1024; N = 512; }
  else             { W = Wo; WT = WoT; K = 512;  N = 1024; }
  int tK = K >> 6;
  int kt = bid % tK, nt = bid / tK;
  int k0 = kt << 6, n0 = nt << 6;
  for (int idx = threadIdx.x; idx < 4096; idx += 256) {
    int r = idx >> 6, c = idx & 63;
    tile[r * 65 + c] = W[(size_t)(k0 + r) * N + n0 + c];
  }
  __syncthreads();
  for (int idx = threadIdx.x; idx < 4096; idx += 256) {
    int r = idx >> 6, c = idx & 63;
    WT[(size_t)(n0 + r) * K + k0 + c] = (bf16_t)tile[c * 65 + r];
  }
}

// ---------- BMx128 GEMM core, BK=64, double-buffered staging, early issue ----------
// LDS: As = sm[0 .. 2*BM*64), Bs = sm[2*BM*64 .. 2*BM*64 + 2*128*64)
// B operand: global_load_lds from pre-swizzled global address (bf16).
// A operand: if AF32, reg-staged from fp32 (issue-early / cvt+ds_write-late),
//            swizzled ds_write_b128; else g2l like B.
// phys chunk = logical chunk ^ (row&7) within each 128-B row.
// mode 0: bf16 out * scale; mode 1: f32 out + bias; mode 2: scatter to Vt.
template<int BM, bool AF32>
__device__ __forceinline__ void gemm_core(bf16_t* sm,
                                          const void* __restrict__ Ap,
                                          const bf16_t* __restrict__ Bt,
                                          int K, int N, int row0, int n0,
                                          int mode, float scale,
                                          bf16_t* __restrict__ Cb,
                                          float* __restrict__ Cf,
                                          const float* __restrict__ bias) {
  constexpr int MI = BM / 32;              // A frag-rows per wave == A staging steps
  bf16_t* As = sm;                         // 2*BM*64 elems
  bf16_t* Bs = sm + 2 * BM * 64;           // 2*128*64 elems
  const int tid = threadIdx.x;
  const int w = tid >> 6, lane = tid & 63, quad = lane >> 4, l16 = lane & 15;

  const int sr8  = lane >> 3;                    // 0..7
  const int slog = ((lane & 7) ^ sr8) << 3;      // logical col (elems)
  const float*  gaF = nullptr;
  const bf16_t* gaB = nullptr;
  {
    size_t aoff = (size_t)(row0 + w * (BM / 4) + sr8) * K + slog;
    if constexpr (AF32) gaF = (const float*)Ap + aoff;
    else                gaB = (const bf16_t*)Ap + aoff;
  }
  const bf16_t* gb = Bt + (size_t)(n0 + w * 32 + sr8) * K + slog;
  bf16_t* lA = As + w * (BM / 4) * 64;           // + buf*BM*64 + p*512
  bf16_t* lB = Bs + w * 2048;                    // + buf*8192  + p*512

  f32x4 acc[MI][4];
#pragma unroll
  for (int i = 0; i < MI; ++i)
#pragma unroll
    for (int j = 0; j < 4; ++j) acc[i][j] = f32x4{0.f, 0.f, 0.f, 0.f};

  const int mrow = (w & 1) * (BM / 2), ncol = (w >> 1) << 6;
  const int KT = K >> 6;

  // prologue: tile 0 -> buf 0
  if constexpr (AF32) {
#pragma unroll
    for (int p = 0; p < MI; ++p) {
      const float* s = gaF + (size_t)(p * 8) * K;
      f32x4 f0 = *(const f32x4*)s;
      f32x4 f1 = *(const f32x4*)(s + 4);
      bf16x8 h;
#pragma unroll
      for (int e = 0; e < 4; ++e) { h[e] = (bf16_t)f0[e]; h[4 + e] = (bf16_t)f1[e]; }
      *(bf16x8*)&lA[p * 512 + lane * 8] = h;
    }
  } else {
#pragma unroll
    for (int p = 0; p < MI; ++p)
      g2l(gaB + (size_t)(p * 8) * K, lA + p * 512);
  }
#pragma unroll
  for (int p = 0; p < 4; ++p)
    g2l(gb + (size_t)(p * 8) * K, lB + p * 512);

  for (int kc = 0; kc < KT; ++kc) {
    const int curA = (kc & 1) * (BM * 64), nxtA = ((kc + 1) & 1) * (BM * 64);
    const int curB = (kc & 1) * 8192,      nxtB = ((kc + 1) & 1) * 8192;
    __syncthreads();              // drains tile-kc loads/writes; publishes buf[cur]
    f32x4 fpre[2 * MI];
    const bool pf = (kc + 1 < KT);
    if (pf) {                     // issue tile kc+1 early; MFMA hides flight
      const int k0 = (kc + 1) * 64;
#pragma unroll
      for (int p = 0; p < 4; ++p)
        g2l(gb + (size_t)(p * 8) * K + k0, lB + nxtB + p * 512);
      if constexpr (AF32) {
#pragma unroll
        for (int p = 0; p < MI; ++p) {
          const float* s = gaF + (size_t)(p * 8) * K + k0;
          fpre[2 * p]     = *(const f32x4*)s;
          fpre[2 * p + 1] = *(const f32x4*)(s + 4);
        }
      } else {
#pragma unroll
        for (int p = 0; p < MI; ++p)
          g2l(gaB + (size_t)(p * 8) * K + k0, lA + nxtA + p * 512);
      }
    }
#pragma unroll
    for (int ks = 0; ks < 2; ++ks) {
      const int phys = ((ks * 4 + quad) ^ (l16 & 7)) << 3;
      bf16x8 af[MI], bfr[4];
#pragma unroll
      for (int i = 0; i < MI; ++i)
        af[i] = *(const bf16x8*)&As[curA + (mrow + i * 16 + l16) * 64 + phys];
#pragma unroll
      for (int j = 0; j < 4; ++j)
        bfr[j] = *(const bf16x8*)&Bs[curB + (ncol + j * 16 + l16) * 64 + phys];
#pragma unroll
      for (int i = 0; i < MI; ++i)
#pragma unroll
        for (int j = 0; j < 4; ++j)
          acc[i][j] = MFMA16(af[i], bfr[j], acc[i][j]);
    }
    if (pf) {
      if constexpr (AF32) {       // write-late: cvt + swizzled ds_write into nxt
#pragma unroll
        for (int p = 0; p < MI; ++p) {
          bf16x8 h;
#pragma unroll
          for (int e = 0; e < 4; ++e) {
            h[e]     = (bf16_t)fpre[2 * p][e];
            h[4 + e] = (bf16_t)fpre[2 * p + 1][e];
          }
          *(bf16x8*)&lA[nxtA + p * 512 + lane * 8] = h;
        }
      }
    }
  }

  // epilogue: C/D layout col=l16, row=quad*4+reg
#pragma unroll
  for (int i = 0; i < MI; ++i) {
    int row = row0 + mrow + i * 16 + quad * 4;
#pragma unroll
    for (int j = 0; j < 4; ++j) {
      int col = n0 + ncol + j * 16 + l16;
      if (mode == 2) {
        // scatter to Vt[bh=b*8+h][d][key]: row -> (b,key), col -> (h,d)
        int bb = row >> 11, key = row & 2047;
        int hh = col >> 6,  d   = col & 63;
        bf16x4 v = { (bf16_t)acc[i][j][0], (bf16_t)acc[i][j][1],
                     (bf16_t)acc[i][j][2], (bf16_t)acc[i][j][3] };
        *(bf16x4*)&Cb[((size_t)((bb * 8 + hh) * 64 + d)) * 2048 + key] = v;
      } else {
#pragma unroll
        for (int r = 0; r < 4; ++r) {
          if (mode == 1) Cf[(size_t)(row + r) * N + col] = acc[i][j][r] + bias[col];
          else           Cb[(size_t)(row + r) * N + col] = (bf16_t)(acc[i][j][r] * scale);
        }
      }
    }
  }
}

// ---------- stage 2: flash attention (512 tiles exactly) ----------
// smem: Ks = sm[0..16384)  Vs = sm[16384..24576)  Ps = sm[24576..33280)
__device__ __forceinline__ void attn_stage(int bid, bf16_t* sm,
                                           const bf16_t* __restrict__ Qb,
                                           const bf16_t* __restrict__ Kb,
                                           const bf16_t* __restrict__ Vt,
                                           bf16_t* __restrict__ AO) {
  bf16_t* Ks = sm;                 // [buf][key][d] rows 128 B, swizzle r&7
  bf16_t* Vs = sm + 16384;         // [d][key]      rows 256 B, swizzle r&15
  bf16_t* Ps = sm + 24576;         // [q][key]      padded, wave-private rows

  const int tid = threadIdx.x;
  const int w = tid >> 6, lane = tid & 63, quad = lane >> 4, l16 = lane & 15;
  const int qt = bid & 31;          // 0..31
  const int bh = bid >> 5;          // 0..15
  const int b = bh >> 3, h = bh & 7;

  const int qrow = b * 2048 + qt * 64 + w * 16 + l16;
  const bf16_t* qptr = Qb + (size_t)qrow * INNER + h * DHEAD;
  bf16x8 bq[2];
  bq[0] = *(const bf16x8*)(qptr + quad * 8);
  bq[1] = *(const bf16x8*)(qptr + 32 + quad * 8);

  f32x4 o[4];
#pragma unroll
  for (int dt = 0; dt < 4; ++dt) o[dt] = f32x4{0.f, 0.f, 0.f, 0.f};
  float m_s = -__builtin_inff(), l_s = 0.f;

  const bf16_t* kbase  = Kb + ((size_t)b * 2048) * INNER + h * DHEAD;
  const bf16_t* vtbase = Vt + ((size_t)bh * 64) * 2048;

  const int krow = lane >> 3;
  const int kcol = ((lane & 7) ^ (lane >> 3)) << 3;
  const int vrow = lane >> 4;

#pragma unroll
  for (int p = 0; p < 4; ++p)
    g2l(kbase + (size_t)(w * 32 + p * 8 + krow) * INNER + kcol,
        &Ks[w * 2048 + p * 512]);

  for (int kt = 0; kt < 16; ++kt) {
    const int cur = (kt & 1) * 8192, nxt = ((kt + 1) & 1) * 8192;
    __syncthreads();
    if (kt < 16 - 1) {
#pragma unroll
      for (int p = 0; p < 4; ++p)
        g2l(kbase + (size_t)((kt + 1) * 128 + w * 32 + p * 8 + krow) * INNER + kcol,
            &Ks[nxt + w * 2048 + p * 512]);
    }
#pragma unroll
    for (int p = 0; p < 4; ++p) {
      int vlog = ((lane & 15) ^ ((p * 4 + vrow) & 15)) << 3;
      g2l(vtbase + (size_t)(w * 16 + p * 4 + vrow) * 2048 + kt * 128 + vlog,
          &Vs[w * 2048 + p * 512]);
    }

    f32x4 s[8];
#pragma unroll
    for (int jt = 0; jt < 8; ++jt) s[jt] = f32x4{0.f, 0.f, 0.f, 0.f};
#pragma unroll
    for (int jt = 0; jt < 8; ++jt) {
#pragma unroll
      for (int ks = 0; ks < 2; ++ks) {
        int phys = ((ks * 4 + quad) ^ (l16 & 7)) << 3;
        bf16x8 ak = *(const bf16x8*)&Ks[cur + (jt * 16 + l16) * 64 + phys];
        s[jt] = MFMA16(ak, bq[ks], s[jt]);
      }
    }

    float mx = -__builtin_inff();
#pragma unroll
    for (int jt = 0; jt < 8; ++jt) {
      float a = fmaxf(fmaxf(s[jt][0], s[jt][1]), fmaxf(s[jt][2], s[jt][3]));
      mx = fmaxf(mx, a);
    }
    mx = fmaxf(mx, __shfl_xor(mx, 16, 64));
    mx = fmaxf(mx, __shfl_xor(mx, 32, 64));
    float mnew = fmaxf(m_s, mx);
    float alpha = __builtin_amdgcn_exp2f(m_s - mnew);
    float rs = 0.f;
#pragma unroll
    for (int jt = 0; jt < 8; ++jt) {
#pragma unroll
      for (int r = 0; r < 4; ++r) {
        float p = __builtin_amdgcn_exp2f(s[jt][r] - mnew);
        s[jt][r] = p;
        rs += p;
      }
    }
    rs += __shfl_xor(rs, 16, 64);
    rs += __shfl_xor(rs, 32, 64);
    l_s = l_s * alpha + rs;
    m_s = mnew;
#pragma unroll
    for (int dt = 0; dt < 4; ++dt) o[dt] *= alpha;

#pragma unroll
    for (int jt = 0; jt < 8; ++jt) {
      bf16x4 pk = { (bf16_t)s[jt][0], (bf16_t)s[jt][1],
                    (bf16_t)s[jt][2], (bf16_t)s[jt][3] };
      *(bf16x4*)&Ps[(w * 16 + l16) * 136 + jt * 16 + quad * 4] = pk;
    }

    __syncthreads();

#pragma unroll
    for (int kc = 0; kc < 4; ++kc) {
      bf16x8 bp = *(const bf16x8*)&Ps[(w * 16 + l16) * 136 + kc * 32 + quad * 8];
#pragma unroll
      for (int dt = 0; dt < 4; ++dt) {
        int phys = ((kc * 4 + quad) ^ l16) << 3;
        bf16x8 av = *(const bf16x8*)&Vs[(dt * 16 + l16) * 128 + phys];
        o[dt] = MFMA16(av, bp, o[dt]);
      }
    }
  }

  float inv = 1.0f / l_s;
#pragma unroll
  for (int dt = 0; dt < 4; ++dt) {
    bf16x4 ov = { (bf16_t)(o[dt][0] * inv), (bf16_t)(o[dt][1] * inv),
                  (bf16_t)(o[dt][2] * inv), (bf16_t)(o[dt][3] * inv) };
    *(bf16x4*)&Ps[(w * 16 + l16) * 136 + dt * 16 + quad * 4] = ov;
  }
  __syncthreads();
  {
    int sr = tid >> 2, sc = (tid & 3) << 4;
    int4 r0 = *(const int4*)&Ps[sr * 136 + sc];
    int4 r1 = *(const int4*)&Ps[sr * 136 + sc + 8];
    bf16_t* aout = AO + ((size_t)(b * 2048 + qt * 64 + sr)) * INNER + h * DHEAD + sc;
    *(int4*)aout       = r0;
    *(int4*)(aout + 8) = r1;
  }
}

// ---------- fused persistent kernel (plain launch, manual co-residency) ----------
// 512 blocks x 256 threads, 66560 B LDS, __launch_bounds__(256,2) -> exactly
// 2 blocks/CU x 256 CUs = 512 co-resident blocks. Stage grids all tile 512:
//   s0 pre_w: 4 matrices x 128 tiles = 512
//   s1 qkv:   Q 128 (BM=128) + K 128 (BM=128) + V 256 (BM=64) = 512
//   s2 attn:  32 qt x 16 bh = 512
//   s3 out:   64 M-tiles (BM=64) x 8 N-tiles = 512
__global__ __launch_bounds__(256, 2) void fused_k(
    const float* __restrict__ x,   const float* __restrict__ ctx,
    const float* __restrict__ Wq,  const float* __restrict__ Wk,
    const float* __restrict__ Wv,  const float* __restrict__ Wo,
    const float* __restrict__ bo,
    bf16_t* __restrict__ WqT, bf16_t* __restrict__ WkT,
    bf16_t* __restrict__ WvT, bf16_t* __restrict__ WoT,
    bf16_t* __restrict__ Qb,  bf16_t* __restrict__ Kb,
    bf16_t* __restrict__ Vt,  bf16_t* __restrict__ AO,
    float* __restrict__ out,  unsigned int* bar) {
  __shared__ __align__(16) bf16_t smem[33280];   // 66560 B
  const int bid = blockIdx.x;

  // stage 0: weight transpose+convert
  pre_w_stage(bid, smem, Wq, Wk, Wv, Wo, WqT, WkT, WvT, WoT);
  gridbar(bar, 1u);

  // stage 1: QKV projections (A = fp32 x/ctx, fused convert)
  if (bid < 128) {
    gemm_core<128, true>(smem, x, WqT, 1024, 512, (bid >> 2) * 128, (bid & 3) * 128,
                         0, QSCALE, Qb, nullptr, nullptr);
  } else if (bid < 256) {
    int t = bid - 128;
    gemm_core<128, true>(smem, ctx, WkT, 1024, 512, (t >> 2) * 128, (t & 3) * 128,
                         0, 1.0f, Kb, nullptr, nullptr);
  } else {
    int t = bid - 256;
    gemm_core<64, true>(smem, ctx, WvT, 1024, 512, (t >> 2) * 64, (t & 3) * 128,
                        2, 1.0f, Vt, nullptr, nullptr);
  }
  gridbar(bar, 2u);

  // stage 2: flash attention
  attn_stage(bid, smem, Qb, Kb, Vt, AO);
  gridbar(bar, 3u);

  // stage 3: output projection + bias
  gemm_core<64, false>(smem, AO, WoT, 512, 1024, (bid >> 3) * 64, (bid & 7) * 128,
                       1, 1.0f, nullptr, out, bo);
}

// ---------- launch ----------
extern "C" void kernel_launch(void* const* d_in, const int* in_sizes, int n_in,
                              void* d_out, int out_size, void* d_ws, size_t ws_size,
                              hipStream_t stream) {
  const float* x   = (const float*)d_in[0];
  const float* ctx = (const float*)d_in[1];
  const float* Wq  = (const float*)d_in[2];
  const float* Wk  = (const float*)d_in[3];
  const float* Wv  = (const float*)d_in[4];
  const float* Wo  = (const float*)d_in[5];
  const float* bo  = (const float*)d_in[6];
  float* out = (float*)d_out;

  char* ws = (char*)d_ws;
  const size_t MB = 1048576;
  bf16_t* WqT = (bf16_t*)(ws + 0 * MB);    //  1 MB  [512][1024]
  bf16_t* WkT = (bf16_t*)(ws + 1 * MB);    //  1 MB
  bf16_t* WvT = (bf16_t*)(ws + 2 * MB);    //  1 MB
  bf16_t* WoT = (bf16_t*)(ws + 3 * MB);    //  1 MB  [1024][512]
  bf16_t* Qb  = (bf16_t*)(ws + 4 * MB);    //  4 MB  [4096][512] (pre-scaled)
  bf16_t* Kb  = (bf16_t*)(ws + 8 * MB);    //  4 MB  [4096][512]
  bf16_t* Vt  = (bf16_t*)(ws + 12 * MB);   //  4 MB  [16][64][2048]
  bf16_t* AO  = (bf16_t*)(ws + 16 * MB);   //  4 MB  [4096][512]
  unsigned int* bar = (unsigned int*)(ws + 20 * MB);

  // workspace is re-poisoned (not zeroed) between iterations: barrier state
  // MUST be explicitly zeroed each launch (round-3 deadlock otherwise).
  hipMemsetAsync((void*)bar, 0, 1024, stream);

  fused_k<<<dim3(512), dim3(256), 0, stream>>>(
      x, ctx, Wq, Wk, Wv, Wo, bo,
      WqT, WkT, WvT, WoT, Qb, Kb, Vt, AO, out, bar);
}

// Round 8
// 166.734 us; speedup vs baseline: 3.5052x; 1.5585x over previous
//
#include <hip/hip_runtime.h>
#include <math.h>

// ---------- types ----------
typedef __bf16 bf16_t;
typedef __bf16 bf16x8 __attribute__((ext_vector_type(8)));
typedef __bf16 bf16x4 __attribute__((ext_vector_type(4)));
typedef float  f32x4  __attribute__((ext_vector_type(4)));

#define MFMA16(a, b, c) __builtin_amdgcn_mfma_f32_16x16x32_bf16((a), (b), (c), 0, 0, 0)

// B=2, N=M=2048, QUERY_DIM=CONTEXT_DIM=1024, HEADS=8, DIM_HEAD=64, INNER=512
#define INNER   512
#define DHEAD   64
// SCALE * log2(e): Q pre-scaled so softmax runs in exp2 domain
#define QSCALE  0.18033688f

// direct HBM -> LDS, 16 B per lane; LDS dest = wave-uniform base + lane*16
__device__ __forceinline__ void g2l(const bf16_t* g, bf16_t* l) {
  __builtin_amdgcn_global_load_lds(
      (const __attribute__((address_space(1))) unsigned int*)g,
      (__attribute__((address_space(3))) unsigned int*)l, 16, 0, 0);
}

// ---------- weight transpose+convert ----------
__global__ __launch_bounds__(256) void pre_w_k(const float* __restrict__ Wq,
                                               const float* __restrict__ Wk,
                                               const float* __restrict__ Wv,
                                               const float* __restrict__ Wo,
                                               bf16_t* __restrict__ WqT,
                                               bf16_t* __restrict__ WkT,
                                               bf16_t* __restrict__ WvT,
                                               bf16_t* __restrict__ WoT) {
  __shared__ float tile[64][65];
  int t = blockIdx.x;               // 0..511, 4 matrices x 128 tiles
  int z = t >> 7, bid = t & 127;
  const float* W; bf16_t* WT; int K, N;
  if (z == 0)      { W = Wq; WT = WqT; K = 1024; N = 512; }
  else if (z == 1) { W = Wk; WT = WkT; K = 1024; N = 512; }
  else if (z == 2) { W = Wv; WT = WvT; K = 1024; N = 512; }
  else             { W = Wo; WT = WoT; K = 512;  N = 1024; }
  int tK = K >> 6;
  int kt = bid % tK, nt = bid / tK;
  int k0 = kt << 6, n0 = nt << 6;
  for (int idx = threadIdx.x; idx < 4096; idx += 256) {
    int r = idx >> 6, c = idx & 63;
    tile[r][c] = W[(size_t)(k0 + r) * N + n0 + c];
  }
  __syncthreads();
  for (int idx = threadIdx.x; idx < 4096; idx += 256) {
    int r = idx >> 6, c = idx & 63;
    WT[(size_t)(n0 + r) * K + k0 + c] = (bf16_t)tile[c][r];
  }
}

// ---------- BMx128 GEMM core, BK=64, double-buffered staging, early issue ----------
// B operand: global_load_lds from pre-swizzled global address (bf16).
// A operand: if AF32, reg-staged from fp32 (issue-early / cvt+ds_write-late);
//            else g2l like B. phys chunk = logical chunk ^ (row&7) per 128-B row.
// mode 0: bf16 out * scale; mode 1: f32 out + bias; mode 2: scatter to Vt.
template<int BM, bool AF32>
__device__ __forceinline__ void gemm_core(const void* __restrict__ Ap,
                                          const bf16_t* __restrict__ Bt,
                                          int K, int N, int row0, int n0,
                                          int mode, float scale,
                                          bf16_t* __restrict__ Cb,
                                          float* __restrict__ Cf,
                                          const float* __restrict__ bias) {
  constexpr int MI = BM / 32;              // A frag-rows per wave == A staging steps
  __shared__ bf16_t As[2 * BM * 64];
  __shared__ bf16_t Bs[2 * 128 * 64];
  const int tid = threadIdx.x;
  const int w = tid >> 6, lane = tid & 63, quad = lane >> 4, l16 = lane & 15;

  const int sr8  = lane >> 3;                    // 0..7
  const int slog = ((lane & 7) ^ sr8) << 3;      // logical col (elems)
  const float*  gaF = nullptr;
  const bf16_t* gaB = nullptr;
  {
    size_t aoff = (size_t)(row0 + w * (BM / 4) + sr8) * K + slog;
    if constexpr (AF32) gaF = (const float*)Ap + aoff;
    else                gaB = (const bf16_t*)Ap + aoff;
  }
  const bf16_t* gb = Bt + (size_t)(n0 + w * 32 + sr8) * K + slog;
  bf16_t* lA = As + w * (BM / 4) * 64;           // + buf*BM*64 + p*512
  bf16_t* lB = Bs + w * 2048;                    // + buf*8192  + p*512

  f32x4 acc[MI][4];
#pragma unroll
  for (int i = 0; i < MI; ++i)
#pragma unroll
    for (int j = 0; j < 4; ++j) acc[i][j] = f32x4{0.f, 0.f, 0.f, 0.f};

  const int mrow = (w & 1) * (BM / 2), ncol = (w >> 1) << 6;
  const int KT = K >> 6;

  // prologue: tile 0 -> buf 0
  if constexpr (AF32) {
#pragma unroll
    for (int p = 0; p < MI; ++p) {
      const float* s = gaF + (size_t)(p * 8) * K;
      f32x4 f0 = *(const f32x4*)s;
      f32x4 f1 = *(const f32x4*)(s + 4);
      bf16x8 h;
#pragma unroll
      for (int e = 0; e < 4; ++e) { h[e] = (bf16_t)f0[e]; h[4 + e] = (bf16_t)f1[e]; }
      *(bf16x8*)&lA[p * 512 + lane * 8] = h;
    }
  } else {
#pragma unroll
    for (int p = 0; p < MI; ++p)
      g2l(gaB + (size_t)(p * 8) * K, lA + p * 512);
  }
#pragma unroll
  for (int p = 0; p < 4; ++p)
    g2l(gb + (size_t)(p * 8) * K, lB + p * 512);

  for (int kc = 0; kc < KT; ++kc) {
    const int curA = (kc & 1) * (BM * 64), nxtA = ((kc + 1) & 1) * (BM * 64);
    const int curB = (kc & 1) * 8192,      nxtB = ((kc + 1) & 1) * 8192;
    __syncthreads();              // drains tile-kc loads/writes; publishes buf[cur]
    f32x4 fpre[2 * MI];
    const bool pf = (kc + 1 < KT);
    if (pf) {                     // issue tile kc+1 early; MFMA hides flight
      const int k0 = (kc + 1) * 64;
#pragma unroll
      for (int p = 0; p < 4; ++p)
        g2l(gb + (size_t)(p * 8) * K + k0, lB + nxtB + p * 512);
      if constexpr (AF32) {
#pragma unroll
        for (int p = 0; p < MI; ++p) {
          const float* s = gaF + (size_t)(p * 8) * K + k0;
          fpre[2 * p]     = *(const f32x4*)s;
          fpre[2 * p + 1] = *(const f32x4*)(s + 4);
        }
      } else {
#pragma unroll
        for (int p = 0; p < MI; ++p)
          g2l(gaB + (size_t)(p * 8) * K + k0, lA + nxtA + p * 512);
      }
    }
#pragma unroll
    for (int ks = 0; ks < 2; ++ks) {
      const int phys = ((ks * 4 + quad) ^ (l16 & 7)) << 3;
      bf16x8 af[MI], bfr[4];
#pragma unroll
      for (int i = 0; i < MI; ++i)
        af[i] = *(const bf16x8*)&As[curA + (mrow + i * 16 + l16) * 64 + phys];
#pragma unroll
      for (int j = 0; j < 4; ++j)
        bfr[j] = *(const bf16x8*)&Bs[curB + (ncol + j * 16 + l16) * 64 + phys];
#pragma unroll
      for (int i = 0; i < MI; ++i)
#pragma unroll
        for (int j = 0; j < 4; ++j)
          acc[i][j] = MFMA16(af[i], bfr[j], acc[i][j]);
    }
    if (pf) {
      if constexpr (AF32) {       // write-late: cvt + swizzled ds_write into nxt
#pragma unroll
        for (int p = 0; p < MI; ++p) {
          bf16x8 h;
#pragma unroll
          for (int e = 0; e < 4; ++e) {
            h[e]     = (bf16_t)fpre[2 * p][e];
            h[4 + e] = (bf16_t)fpre[2 * p + 1][e];
          }
          *(bf16x8*)&lA[nxtA + p * 512 + lane * 8] = h;
        }
      }
    }
  }

  // epilogue: C/D layout col=l16, row=quad*4+reg
#pragma unroll
  for (int i = 0; i < MI; ++i) {
    int row = row0 + mrow + i * 16 + quad * 4;
#pragma unroll
    for (int j = 0; j < 4; ++j) {
      int col = n0 + ncol + j * 16 + l16;
      if (mode == 2) {
        // scatter to Vt[bh=b*8+h][d][key]: row -> (b,key), col -> (h,d)
        int bb = row >> 11, key = row & 2047;
        int hh = col >> 6,  d   = col & 63;
        bf16x4 v = { (bf16_t)acc[i][j][0], (bf16_t)acc[i][j][1],
                     (bf16_t)acc[i][j][2], (bf16_t)acc[i][j][3] };
        *(bf16x4*)&Cb[((size_t)((bb * 8 + hh) * 64 + d)) * 2048 + key] = v;
      } else {
#pragma unroll
        for (int r = 0; r < 4; ++r) {
          if (mode == 1) Cf[(size_t)(row + r) * N + col] = acc[i][j][r] + bias[col];
          else           Cb[(size_t)(row + r) * N + col] = (bf16_t)(acc[i][j][r] * scale);
        }
      }
    }
  }
}

// ---------- QKV: 1-D grid 384, XCD-aware m-grouping ----------
// Dispatch round-robins linear bid across 8 XCDs (xcd = bid&7). Group all 4
// n-tiles of 4 m-panels on ONE XCD so each A-panel (512 KB fp32) is fetched
// into exactly one L2 (was 4 XCDs -> 4x fetch amplification).
__global__ __launch_bounds__(256, 2) void gemm_qkv_k(const float* __restrict__ x,
                                                     const float* __restrict__ ctx,
                                                     const bf16_t* __restrict__ WqT,
                                                     const bf16_t* __restrict__ WkT,
                                                     const bf16_t* __restrict__ WvT,
                                                     bf16_t* __restrict__ Qb,
                                                     bf16_t* __restrict__ Kb,
                                                     bf16_t* __restrict__ Vt) {
  int bid = blockIdx.x;             // 0..383
  int z = bid >> 7;                 // 0=Q 1=K 2=V (128 blocks each; 128%8==0)
  int xcd  = bid & 7;
  int slot = (bid & 127) >> 3;      // 0..15
  int m = (xcd << 2) | (slot >> 2); // 0..31: XCD x owns m in [4x, 4x+4)
  int n = slot & 3;
  const float* A   = (z == 0) ? x   : ctx;
  const bf16_t* Bt = (z == 0) ? WqT : (z == 1) ? WkT : WvT;
  bf16_t* C        = (z == 0) ? Qb  : (z == 1) ? Kb  : Vt;
  int mode         = (z == 2) ? 2 : 0;
  float scale      = (z == 0) ? QSCALE : 1.0f;
  gemm_core<128, true>(A, Bt, 1024, 512, m * 128, n * 128, mode, scale,
                       C, nullptr, nullptr);
}

// ---------- out-proj: 1-D grid 512, XCD-aware m-grouping ----------
// XCD x owns 8 m-panels (all 8 n-tiles) -> AO fetched 1x (was 8x).
__global__ __launch_bounds__(256, 2) void gemm_out_k(const bf16_t* __restrict__ AO,
                                                     const bf16_t* __restrict__ WoT,
                                                     const float* __restrict__ bo,
                                                     float* __restrict__ out) {
  int bid = blockIdx.x;             // 0..511
  int xcd  = bid & 7;
  int slot = bid >> 3;              // 0..63
  int m = (xcd << 3) | (slot >> 3); // 0..63
  int n = slot & 7;
  gemm_core<64, false>(AO, WoT, 512, 1024, m * 64, n * 128,
                       1, 1.0f, nullptr, out, bo);
}

// ---------- flash attention: 1-D grid 512, XCD-aware bh-grouping ----------
// XCD x owns bh in {2x, 2x+1}: the 32 qt-blocks sharing a bh's K/V slice
// (512 KB) all land on one XCD -> K/V fetched 1x into that L2 (was ~8x).
__global__ __launch_bounds__(256, 2) void attn_k(const bf16_t* __restrict__ Qb,
                                                 const bf16_t* __restrict__ Kb,
                                                 const bf16_t* __restrict__ Vt,
                                                 bf16_t* __restrict__ AO) {
  const int tid = threadIdx.x;
  const int w = tid >> 6, lane = tid & 63, quad = lane >> 4, l16 = lane & 15;
  int bid = blockIdx.x;             // 0..511
  int xcd  = bid & 7;
  int slot = bid >> 3;              // 0..63
  const int qt = slot & 31;         // 0..31
  const int bh = (xcd << 1) | (slot >> 5);   // 0..15
  const int b = bh >> 3, h = bh & 7;

  __shared__ bf16_t Ks[2 * 128 * 64];  // [buf][key][d] rows 128 B, swizzle r&7
  __shared__ bf16_t Vs[64 * 128];      // [d][key]      rows 256 B, swizzle r&15
  __shared__ bf16_t Ps[64 * 136];      // [q][key]      padded, wave-private rows

  const int qrow = b * 2048 + qt * 64 + w * 16 + l16;
  const bf16_t* qptr = Qb + (size_t)qrow * INNER + h * DHEAD;
  bf16x8 bq[2];
  bq[0] = *(const bf16x8*)(qptr + quad * 8);
  bq[1] = *(const bf16x8*)(qptr + 32 + quad * 8);

  f32x4 o[4];
#pragma unroll
  for (int dt = 0; dt < 4; ++dt) o[dt] = f32x4{0.f, 0.f, 0.f, 0.f};
  float m_s = -__builtin_inff(), l_s = 0.f;

  const bf16_t* kbase  = Kb + ((size_t)b * 2048) * INNER + h * DHEAD;
  const bf16_t* vtbase = Vt + ((size_t)bh * 64) * 2048;

  const int krow = lane >> 3;
  const int kcol = ((lane & 7) ^ (lane >> 3)) << 3;
  const int vrow = lane >> 4;

#pragma unroll
  for (int p = 0; p < 4; ++p)
    g2l(kbase + (size_t)(w * 32 + p * 8 + krow) * INNER + kcol,
        &Ks[w * 2048 + p * 512]);

  for (int kt = 0; kt < 16; ++kt) {
    const int cur = (kt & 1) * 8192, nxt = ((kt + 1) & 1) * 8192;
    __syncthreads();
    if (kt < 16 - 1) {
#pragma unroll
      for (int p = 0; p < 4; ++p)
        g2l(kbase + (size_t)((kt + 1) * 128 + w * 32 + p * 8 + krow) * INNER + kcol,
            &Ks[nxt + w * 2048 + p * 512]);
    }
#pragma unroll
    for (int p = 0; p < 4; ++p) {
      int vlog = ((lane & 15) ^ ((p * 4 + vrow) & 15)) << 3;
      g2l(vtbase + (size_t)(w * 16 + p * 4 + vrow) * 2048 + kt * 128 + vlog,
          &Vs[w * 2048 + p * 512]);
    }

    f32x4 s[8];
#pragma unroll
    for (int jt = 0; jt < 8; ++jt) s[jt] = f32x4{0.f, 0.f, 0.f, 0.f};
#pragma unroll
    for (int jt = 0; jt < 8; ++jt) {
#pragma unroll
      for (int ks = 0; ks < 2; ++ks) {
        int phys = ((ks * 4 + quad) ^ (l16 & 7)) << 3;
        bf16x8 ak = *(const bf16x8*)&Ks[cur + (jt * 16 + l16) * 64 + phys];
        s[jt] = MFMA16(ak, bq[ks], s[jt]);
      }
    }

    float mx = -__builtin_inff();
#pragma unroll
    for (int jt = 0; jt < 8; ++jt) {
      float a = fmaxf(fmaxf(s[jt][0], s[jt][1]), fmaxf(s[jt][2], s[jt][3]));
      mx = fmaxf(mx, a);
    }
    mx = fmaxf(mx, __shfl_xor(mx, 16, 64));
    mx = fmaxf(mx, __shfl_xor(mx, 32, 64));
    float mnew = fmaxf(m_s, mx);
    float alpha = __builtin_amdgcn_exp2f(m_s - mnew);
    float rs = 0.f;
#pragma unroll
    for (int jt = 0; jt < 8; ++jt) {
#pragma unroll
      for (int r = 0; r < 4; ++r) {
        float p = __builtin_amdgcn_exp2f(s[jt][r] - mnew);
        s[jt][r] = p;
        rs += p;
      }
    }
    rs += __shfl_xor(rs, 16, 64);
    rs += __shfl_xor(rs, 32, 64);
    l_s = l_s * alpha + rs;
    m_s = mnew;
#pragma unroll
    for (int dt = 0; dt < 4; ++dt) o[dt] *= alpha;

#pragma unroll
    for (int jt = 0; jt < 8; ++jt) {
      bf16x4 pk = { (bf16_t)s[jt][0], (bf16_t)s[jt][1],
                    (bf16_t)s[jt][2], (bf16_t)s[jt][3] };
      *(bf16x4*)&Ps[(w * 16 + l16) * 136 + jt * 16 + quad * 4] = pk;
    }

    __syncthreads();

#pragma unroll
    for (int kc = 0; kc < 4; ++kc) {
      bf16x8 bp = *(const bf16x8*)&Ps[(w * 16 + l16) * 136 + kc * 32 + quad * 8];
#pragma unroll
      for (int dt = 0; dt < 4; ++dt) {
        int phys = ((kc * 4 + quad) ^ l16) << 3;
        bf16x8 av = *(const bf16x8*)&Vs[(dt * 16 + l16) * 128 + phys];
        o[dt] = MFMA16(av, bp, o[dt]);
      }
    }
  }

  float inv = 1.0f / l_s;
#pragma unroll
  for (int dt = 0; dt < 4; ++dt) {
    bf16x4 ov = { (bf16_t)(o[dt][0] * inv), (bf16_t)(o[dt][1] * inv),
                  (bf16_t)(o[dt][2] * inv), (bf16_t)(o[dt][3] * inv) };
    *(bf16x4*)&Ps[(w * 16 + l16) * 136 + dt * 16 + quad * 4] = ov;
  }
  __syncthreads();
  {
    int sr = tid >> 2, sc = (tid & 3) << 4;
    int4 r0 = *(const int4*)&Ps[sr * 136 + sc];
    int4 r1 = *(const int4*)&Ps[sr * 136 + sc + 8];
    bf16_t* aout = AO + ((size_t)(b * 2048 + qt * 64 + sr)) * INNER + h * DHEAD + sc;
    *(int4*)aout       = r0;
    *(int4*)(aout + 8) = r1;
  }
}

// ---------- launch ----------
extern "C" void kernel_launch(void* const* d_in, const int* in_sizes, int n_in,
                              void* d_out, int out_size, void* d_ws, size_t ws_size,
                              hipStream_t stream) {
  const float* x   = (const float*)d_in[0];
  const float* ctx = (const float*)d_in[1];
  const float* Wq  = (const float*)d_in[2];
  const float* Wk  = (const float*)d_in[3];
  const float* Wv  = (const float*)d_in[4];
  const float* Wo  = (const float*)d_in[5];
  const float* bo  = (const float*)d_in[6];
  float* out = (float*)d_out;

  char* ws = (char*)d_ws;
  const size_t MB = 1048576;
  bf16_t* WqT = (bf16_t*)(ws + 0 * MB);    //  1 MB  [512][1024]
  bf16_t* WkT = (bf16_t*)(ws + 1 * MB);    //  1 MB
  bf16_t* WvT = (bf16_t*)(ws + 2 * MB);    //  1 MB
  bf16_t* WoT = (bf16_t*)(ws + 3 * MB);    //  1 MB  [1024][512]
  bf16_t* Qb  = (bf16_t*)(ws + 4 * MB);    //  4 MB  [4096][512] (pre-scaled)
  bf16_t* Kb  = (bf16_t*)(ws + 8 * MB);    //  4 MB  [4096][512]
  bf16_t* Vt  = (bf16_t*)(ws + 12 * MB);   //  4 MB  [16][64][2048]
  bf16_t* AO  = (bf16_t*)(ws + 16 * MB);   //  4 MB  [4096][512]

  pre_w_k<<<512, 256, 0, stream>>>(Wq, Wk, Wv, Wo, WqT, WkT, WvT, WoT);
  gemm_qkv_k<<<384, 256, 0, stream>>>(x, ctx, WqT, WkT, WvT, Qb, Kb, Vt);
  attn_k<<<512, 256, 0, stream>>>(Qb, Kb, Vt, AO);
  gemm_out_k<<<512, 256, 0, stream>>>(AO, WoT, bo, out);
}

// Round 10
// 162.159 us; speedup vs baseline: 3.6041x; 1.0282x over previous
//
#include <hip/hip_runtime.h>
#include <math.h>

// ---------- types ----------
typedef __bf16 bf16_t;
typedef __bf16 bf16x8 __attribute__((ext_vector_type(8)));
typedef __bf16 bf16x4 __attribute__((ext_vector_type(4)));
typedef float  f32x4  __attribute__((ext_vector_type(4)));

#define MFMA16(a, b, c) __builtin_amdgcn_mfma_f32_16x16x32_bf16((a), (b), (c), 0, 0, 0)

// B=2, N=M=2048, QUERY_DIM=CONTEXT_DIM=1024, HEADS=8, DIM_HEAD=64, INNER=512
#define INNER   512
#define DHEAD   64
// SCALE * log2(e): Q pre-scaled so softmax runs in exp2 domain
#define QSCALE  0.18033688f

// direct HBM -> LDS, 16 B per lane; LDS dest = wave-uniform base + lane*16
__device__ __forceinline__ void g2l(const bf16_t* g, bf16_t* l) {
  __builtin_amdgcn_global_load_lds(
      (const __attribute__((address_space(1))) unsigned int*)g,
      (__attribute__((address_space(3))) unsigned int*)l, 16, 0, 0);
}

// ---------- weight transpose+convert ----------
__global__ __launch_bounds__(256) void pre_w_k(const float* __restrict__ Wq,
                                               const float* __restrict__ Wk,
                                               const float* __restrict__ Wv,
                                               const float* __restrict__ Wo,
                                               bf16_t* __restrict__ WqT,
                                               bf16_t* __restrict__ WkT,
                                               bf16_t* __restrict__ WvT,
                                               bf16_t* __restrict__ WoT) {
  __shared__ float tile[64][65];
  int t = blockIdx.x;               // 0..511, 4 matrices x 128 tiles
  int z = t >> 7, bid = t & 127;
  const float* W; bf16_t* WT; int K, N;
  if (z == 0)      { W = Wq; WT = WqT; K = 1024; N = 512; }
  else if (z == 1) { W = Wk; WT = WkT; K = 1024; N = 512; }
  else if (z == 2) { W = Wv; WT = WvT; K = 1024; N = 512; }
  else             { W = Wo; WT = WoT; K = 512;  N = 1024; }
  int tK = K >> 6;
  int kt = bid % tK, nt = bid / tK;
  int k0 = kt << 6, n0 = nt << 6;
  for (int idx = threadIdx.x; idx < 4096; idx += 256) {
    int r = idx >> 6, c = idx & 63;
    tile[r][c] = W[(size_t)(k0 + r) * N + n0 + c];
  }
  __syncthreads();
  for (int idx = threadIdx.x; idx < 4096; idx += 256) {
    int r = idx >> 6, c = idx & 63;
    WT[(size_t)(n0 + r) * K + k0 + c] = (bf16_t)tile[c][r];
  }
}

// ---------- qkv GEMM core: 128x128, BK=64, counted-vmcnt pipeline ----------
// A = fp32 (x/ctx), reg-staged depth-2 (ping-pong pA0/pA1, static indexing);
// B = bf16 W^T via global_load_lds (pre-swizzled source).
// Raw s_barrier + counted s_waitcnt: per-wave 12 vmem ops/step (4 B g2l + 8 A
// loads), issued in fixed order -> deterministic counts:
//   top:  vmcnt(8)  = B(kc) landed; A(kc+1) [8 newer] stays in flight
//   tail: vmcnt(12) = A(kc+1) landed; B(kc+1)+A(kc+2) [12 newer] stay in flight
// Tail steps issue wrap-around dummy loads to keep counts uniform (they only
// overwrite buffers nobody reads again). sched_barrier(0) after each asm wait
// (rule: compiler hoists reg-only MFMA past asm waitcnt otherwise).
#define QKV_STEP(kc, CUR, NXT, PRC, PRF)                                         \
  {                                                                              \
    asm volatile("s_waitcnt vmcnt(8) lgkmcnt(0)" ::: "memory");                  \
    __builtin_amdgcn_s_barrier();                                                \
    __builtin_amdgcn_sched_barrier(0);                                           \
    {                                                                            \
      const int k0b = (((kc) + 1) & (KT - 1)) * 64;                              \
      _Pragma("unroll")                                                          \
      for (int p = 0; p < 4; ++p)                                                \
        g2l(gb + (size_t)(p * 8) * K + k0b, lB + (NXT) + p * 512);               \
    }                                                                            \
    {                                                                            \
      const int k0a = (((kc) + 2) & (KT - 1)) * 64;                              \
      _Pragma("unroll")                                                          \
      for (int p = 0; p < 4; ++p) {                                              \
        const float* s_ = ga + (size_t)(p * 8) * K + k0a;                        \
        PRF[2 * p]     = *(const f32x4*)s_;                                      \
        PRF[2 * p + 1] = *(const f32x4*)(s_ + 4);                                \
      }                                                                          \
    }                                                                            \
    _Pragma("unroll")                                                            \
    for (int ks = 0; ks < 2; ++ks) {                                             \
      const int phys = ((ks * 4 + quad) ^ (l16 & 7)) << 3;                       \
      bf16x8 af[4], bfr[4];                                                      \
      _Pragma("unroll")                                                          \
      for (int i = 0; i < 4; ++i)                                                \
        af[i] = *(const bf16x8*)&As[(CUR) + (mrow + i * 16 + l16) * 64 + phys];  \
      _Pragma("unroll")                                                          \
      for (int j = 0; j < 4; ++j)                                                \
        bfr[j] = *(const bf16x8*)&Bs[(CUR) + (ncol + j * 16 + l16) * 64 + phys]; \
      _Pragma("unroll")                                                          \
      for (int i = 0; i < 4; ++i)                                                \
        _Pragma("unroll")                                                        \
        for (int j = 0; j < 4; ++j)                                              \
          acc[i][j] = MFMA16(af[i], bfr[j], acc[i][j]);                          \
    }                                                                            \
    asm volatile("s_waitcnt vmcnt(12)" ::: "memory");                            \
    __builtin_amdgcn_sched_barrier(0);                                           \
    _Pragma("unroll")                                                            \
    for (int p = 0; p < 4; ++p) {                                                \
      bf16x8 h_;                                                                 \
      _Pragma("unroll")                                                          \
      for (int e = 0; e < 4; ++e) {                                              \
        h_[e]     = (bf16_t)PRC[2 * p][e];                                       \
        h_[4 + e] = (bf16_t)PRC[2 * p + 1][e];                                   \
      }                                                                          \
      *(bf16x8*)&lA[(NXT) + p * 512 + lane * 8] = h_;                            \
    }                                                                            \
  }

__device__ __forceinline__ void gemm_qkv_core(const float* __restrict__ A,
                                              const bf16_t* __restrict__ Bt,
                                              int row0, int n0,
                                              int mode, float scale,
                                              bf16_t* __restrict__ Cb) {
  constexpr int K = 1024, KT = 16;
  __shared__ bf16_t As[2 * 128 * 64];   // 32 KB
  __shared__ bf16_t Bs[2 * 128 * 64];   // 32 KB
  const int tid = threadIdx.x;
  const int w = tid >> 6, lane = tid & 63, quad = lane >> 4, l16 = lane & 15;
  const int sr8  = lane >> 3;
  const int slog = ((lane & 7) ^ sr8) << 3;
  const float*  ga = A  + (size_t)(row0 + w * 32 + sr8) * K + slog;
  const bf16_t* gb = Bt + (size_t)(n0   + w * 32 + sr8) * K + slog;
  bf16_t* lA = As + w * 2048;
  bf16_t* lB = Bs + w * 2048;

  f32x4 acc[4][4];
#pragma unroll
  for (int i = 0; i < 4; ++i)
#pragma unroll
    for (int j = 0; j < 4; ++j) acc[i][j] = f32x4{0.f, 0.f, 0.f, 0.f};

  f32x4 pA0[8], pA1[8];                 // ping-pong A prefetch (static names)
  const int mrow = (w & 1) << 6, ncol = (w >> 1) << 6;

  // prologue: A(0) direct cvt -> As[0]; issue B(0) g2l; issue A(1) -> pA0
#pragma unroll
  for (int p = 0; p < 4; ++p) {
    const float* s = ga + (size_t)(p * 8) * K;
    f32x4 f0 = *(const f32x4*)s;
    f32x4 f1 = *(const f32x4*)(s + 4);
    bf16x8 h;
#pragma unroll
    for (int e = 0; e < 4; ++e) { h[e] = (bf16_t)f0[e]; h[4 + e] = (bf16_t)f1[e]; }
    *(bf16x8*)&lA[p * 512 + lane * 8] = h;
  }
#pragma unroll
  for (int p = 0; p < 4; ++p)
    g2l(gb + (size_t)(p * 8) * K, lB + p * 512);
#pragma unroll
  for (int p = 0; p < 4; ++p) {
    const float* s = ga + (size_t)(p * 8) * K + 64;
    pA0[2 * p]     = *(const f32x4*)s;
    pA0[2 * p + 1] = *(const f32x4*)(s + 4);
  }

  for (int kc = 0; kc < KT; kc += 2) {
    QKV_STEP(kc,     0,    8192, pA0, pA1);
    QKV_STEP(kc + 1, 8192, 0,    pA1, pA0);
  }

  // epilogue: C/D layout col=l16, row=quad*4+reg
#pragma unroll
  for (int i = 0; i < 4; ++i) {
    int row = row0 + mrow + i * 16 + quad * 4;
#pragma unroll
    for (int j = 0; j < 4; ++j) {
      int col = n0 + ncol + j * 16 + l16;
      if (mode == 2) {
        // scatter to Vt[bh=b*8+h][d][key]: row -> (b,key), col -> (h,d)
        int bb = row >> 11, key = row & 2047;
        int hh = col >> 6,  d   = col & 63;
        bf16x4 v = { (bf16_t)acc[i][j][0], (bf16_t)acc[i][j][1],
                     (bf16_t)acc[i][j][2], (bf16_t)acc[i][j][3] };
        *(bf16x4*)&Cb[((size_t)((bb * 8 + hh) * 64 + d)) * 2048 + key] = v;
      } else {
#pragma unroll
        for (int r = 0; r < 4; ++r)
          Cb[(size_t)(row + r) * 512 + col] = (bf16_t)(acc[i][j][r] * scale);
      }
    }
  }
}

// ---------- generic BMx128 GEMM core (used by out-proj; bf16 A via g2l) ----------
template<int BM>
__device__ __forceinline__ void gemm_core(const bf16_t* __restrict__ Ab,
                                          const bf16_t* __restrict__ Bt,
                                          int K, int N, int row0, int n0,
                                          float* __restrict__ Cf,
                                          const float* __restrict__ bias) {
  constexpr int MI = BM / 32;
  __shared__ bf16_t As[2 * BM * 64];
  __shared__ bf16_t Bs[2 * 128 * 64];
  const int tid = threadIdx.x;
  const int w = tid >> 6, lane = tid & 63, quad = lane >> 4, l16 = lane & 15;

  const int sr8  = lane >> 3;
  const int slog = ((lane & 7) ^ sr8) << 3;
  const bf16_t* ga = Ab + (size_t)(row0 + w * (BM / 4) + sr8) * K + slog;
  const bf16_t* gb = Bt + (size_t)(n0   + w * 32 + sr8) * K + slog;
  bf16_t* lA = As + w * (BM / 4) * 64;
  bf16_t* lB = Bs + w * 2048;

  f32x4 acc[MI][4];
#pragma unroll
  for (int i = 0; i < MI; ++i)
#pragma unroll
    for (int j = 0; j < 4; ++j) acc[i][j] = f32x4{0.f, 0.f, 0.f, 0.f};

  const int mrow = (w & 1) * (BM / 2), ncol = (w >> 1) << 6;
  const int KT = K >> 6;

#pragma unroll
  for (int p = 0; p < MI; ++p)
    g2l(ga + (size_t)(p * 8) * K, lA + p * 512);
#pragma unroll
  for (int p = 0; p < 4; ++p)
    g2l(gb + (size_t)(p * 8) * K, lB + p * 512);

  for (int kc = 0; kc < KT; ++kc) {
    const int curA = (kc & 1) * (BM * 64), nxtA = ((kc + 1) & 1) * (BM * 64);
    const int curB = (kc & 1) * 8192,      nxtB = ((kc + 1) & 1) * 8192;
    __syncthreads();
    if (kc + 1 < KT) {
      const int k0 = (kc + 1) * 64;
#pragma unroll
      for (int p = 0; p < MI; ++p)
        g2l(ga + (size_t)(p * 8) * K + k0, lA + nxtA + p * 512);
#pragma unroll
      for (int p = 0; p < 4; ++p)
        g2l(gb + (size_t)(p * 8) * K + k0, lB + nxtB + p * 512);
    }
#pragma unroll
    for (int ks = 0; ks < 2; ++ks) {
      const int phys = ((ks * 4 + quad) ^ (l16 & 7)) << 3;
      bf16x8 af[MI], bfr[4];
#pragma unroll
      for (int i = 0; i < MI; ++i)
        af[i] = *(const bf16x8*)&As[curA + (mrow + i * 16 + l16) * 64 + phys];
#pragma unroll
      for (int j = 0; j < 4; ++j)
        bfr[j] = *(const bf16x8*)&Bs[curB + (ncol + j * 16 + l16) * 64 + phys];
#pragma unroll
      for (int i = 0; i < MI; ++i)
#pragma unroll
        for (int j = 0; j < 4; ++j)
          acc[i][j] = MFMA16(af[i], bfr[j], acc[i][j]);
    }
  }

#pragma unroll
  for (int i = 0; i < MI; ++i) {
    int row = row0 + mrow + i * 16 + quad * 4;
#pragma unroll
    for (int j = 0; j < 4; ++j) {
      int col = n0 + ncol + j * 16 + l16;
#pragma unroll
      for (int r = 0; r < 4; ++r)
        Cf[(size_t)(row + r) * N + col] = acc[i][j][r] + bias[col];
    }
  }
}

// ---------- QKV: 1-D grid 384, XCD-aware m-grouping ----------
__global__ __launch_bounds__(256, 2) void gemm_qkv_k(const float* __restrict__ x,
                                                     const float* __restrict__ ctx,
                                                     const bf16_t* __restrict__ WqT,
                                                     const bf16_t* __restrict__ WkT,
                                                     const bf16_t* __restrict__ WvT,
                                                     bf16_t* __restrict__ Qb,
                                                     bf16_t* __restrict__ Kb,
                                                     bf16_t* __restrict__ Vt) {
  int bid = blockIdx.x;             // 0..383
  int z = bid >> 7;                 // 0=Q 1=K 2=V (128 blocks each)
  int xcd  = bid & 7;
  int slot = (bid & 127) >> 3;      // 0..15
  int m = (xcd << 2) | (slot >> 2); // XCD x owns m in [4x, 4x+4)
  int n = slot & 3;
  const float* A   = (z == 0) ? x   : ctx;
  const bf16_t* Bt = (z == 0) ? WqT : (z == 1) ? WkT : WvT;
  bf16_t* C        = (z == 0) ? Qb  : (z == 1) ? Kb  : Vt;
  int mode         = (z == 2) ? 2 : 0;
  float scale      = (z == 0) ? QSCALE : 1.0f;
  gemm_qkv_core(A, Bt, m * 128, n * 128, mode, scale, C);
}

// ---------- out-proj: 1-D grid 512, XCD-aware m-grouping ----------
__global__ __launch_bounds__(256, 2) void gemm_out_k(const bf16_t* __restrict__ AO,
                                                     const bf16_t* __restrict__ WoT,
                                                     const float* __restrict__ bo,
                                                     float* __restrict__ out) {
  int bid = blockIdx.x;             // 0..511
  int xcd  = bid & 7;
  int slot = bid >> 3;              // 0..63
  int m = (xcd << 3) | (slot >> 3); // 0..63
  int n = slot & 7;
  gemm_core<64>(AO, WoT, 512, 1024, m * 64, n * 128, out, bo);
}

// ---------- flash attention: 1-D grid 512, XCD-aware bh-grouping ----------
__global__ __launch_bounds__(256, 2) void attn_k(const bf16_t* __restrict__ Qb,
                                                 const bf16_t* __restrict__ Kb,
                                                 const bf16_t* __restrict__ Vt,
                                                 bf16_t* __restrict__ AO) {
  const int tid = threadIdx.x;
  const int w = tid >> 6, lane = tid & 63, quad = lane >> 4, l16 = lane & 15;
  int bid = blockIdx.x;             // 0..511
  int xcd  = bid & 7;
  int slot = bid >> 3;              // 0..63
  const int qt = slot & 31;         // 0..31
  const int bh = (xcd << 1) | (slot >> 5);   // 0..15
  const int b = bh >> 3, h = bh & 7;

  __shared__ bf16_t Ks[2 * 128 * 64];  // [buf][key][d] rows 128 B, swizzle r&7
  __shared__ bf16_t Vs[64 * 128];      // [d][key]      rows 256 B, swizzle r&15
  __shared__ bf16_t Ps[64 * 136];      // [q][key]      padded, wave-private rows

  const int qrow = b * 2048 + qt * 64 + w * 16 + l16;
  const bf16_t* qptr = Qb + (size_t)qrow * INNER + h * DHEAD;
  bf16x8 bq[2];
  bq[0] = *(const bf16x8*)(qptr + quad * 8);
  bq[1] = *(const bf16x8*)(qptr + 32 + quad * 8);

  f32x4 o[4];
#pragma unroll
  for (int dt = 0; dt < 4; ++dt) o[dt] = f32x4{0.f, 0.f, 0.f, 0.f};
  float m_s = -__builtin_inff(), l_s = 0.f;

  const bf16_t* kbase  = Kb + ((size_t)b * 2048) * INNER + h * DHEAD;
  const bf16_t* vtbase = Vt + ((size_t)bh * 64) * 2048;

  const int krow = lane >> 3;
  const int kcol = ((lane & 7) ^ (lane >> 3)) << 3;
  const int vrow = lane >> 4;

#pragma unroll
  for (int p = 0; p < 4; ++p)
    g2l(kbase + (size_t)(w * 32 + p * 8 + krow) * INNER + kcol,
        &Ks[w * 2048 + p * 512]);

  for (int kt = 0; kt < 16; ++kt) {
    const int cur = (kt & 1) * 8192, nxt = ((kt + 1) & 1) * 8192;
    __syncthreads();
    if (kt < 16 - 1) {
#pragma unroll
      for (int p = 0; p < 4; ++p)
        g2l(kbase + (size_t)((kt + 1) * 128 + w * 32 + p * 8 + krow) * INNER + kcol,
            &Ks[nxt + w * 2048 + p * 512]);
    }
#pragma unroll
    for (int p = 0; p < 4; ++p) {
      int vlog = ((lane & 15) ^ ((p * 4 + vrow) & 15)) << 3;
      g2l(vtbase + (size_t)(w * 16 + p * 4 + vrow) * 2048 + kt * 128 + vlog,
          &Vs[w * 2048 + p * 512]);
    }

    f32x4 s[8];
#pragma unroll
    for (int jt = 0; jt < 8; ++jt) s[jt] = f32x4{0.f, 0.f, 0.f, 0.f};
    __builtin_amdgcn_s_setprio(1);      // T5: favor MFMA wave on CU scheduler
#pragma unroll
    for (int jt = 0; jt < 8; ++jt) {
#pragma unroll
      for (int ks = 0; ks < 2; ++ks) {
        int phys = ((ks * 4 + quad) ^ (l16 & 7)) << 3;
        bf16x8 ak = *(const bf16x8*)&Ks[cur + (jt * 16 + l16) * 64 + phys];
        s[jt] = MFMA16(ak, bq[ks], s[jt]);
      }
    }
    __builtin_amdgcn_s_setprio(0);

    float mx = -__builtin_inff();
#pragma unroll
    for (int jt = 0; jt < 8; ++jt) {
      float a = fmaxf(fmaxf(s[jt][0], s[jt][1]), fmaxf(s[jt][2], s[jt][3]));
      mx = fmaxf(mx, a);
    }
    mx = fmaxf(mx, __shfl_xor(mx, 16, 64));
    mx = fmaxf(mx, __shfl_xor(mx, 32, 64));
    float mnew = fmaxf(m_s, mx);
    float alpha = __builtin_amdgcn_exp2f(m_s - mnew);
    float rs = 0.f;
#pragma unroll
    for (int jt = 0; jt < 8; ++jt) {
#pragma unroll
      for (int r = 0; r < 4; ++r) {
        float p = __builtin_amdgcn_exp2f(s[jt][r] - mnew);
        s[jt][r] = p;
        rs += p;
      }
    }
    rs += __shfl_xor(rs, 16, 64);
    rs += __shfl_xor(rs, 32, 64);
    l_s = l_s * alpha + rs;
    m_s = mnew;
#pragma unroll
    for (int dt = 0; dt < 4; ++dt) o[dt] *= alpha;

#pragma unroll
    for (int jt = 0; jt < 8; ++jt) {
      bf16x4 pk = { (bf16_t)s[jt][0], (bf16_t)s[jt][1],
                    (bf16_t)s[jt][2], (bf16_t)s[jt][3] };
      *(bf16x4*)&Ps[(w * 16 + l16) * 136 + jt * 16 + quad * 4] = pk;
    }

    __syncthreads();

    __builtin_amdgcn_s_setprio(1);
#pragma unroll
    for (int kc = 0; kc < 4; ++kc) {
      bf16x8 bp = *(const bf16x8*)&Ps[(w * 16 + l16) * 136 + kc * 32 + quad * 8];
#pragma unroll
      for (int dt = 0; dt < 4; ++dt) {
        int phys = ((kc * 4 + quad) ^ l16) << 3;
        bf16x8 av = *(const bf16x8*)&Vs[(dt * 16 + l16) * 128 + phys];
        o[dt] = MFMA16(av, bp, o[dt]);
      }
    }
    __builtin_amdgcn_s_setprio(0);
  }

  float inv = 1.0f / l_s;
#pragma unroll
  for (int dt = 0; dt < 4; ++dt) {
    bf16x4 ov = { (bf16_t)(o[dt][0] * inv), (bf16_t)(o[dt][1] * inv),
                  (bf16_t)(o[dt][2] * inv), (bf16_t)(o[dt][3] * inv) };
    *(bf16x4*)&Ps[(w * 16 + l16) * 136 + dt * 16 + quad * 4] = ov;
  }
  __syncthreads();
  {
    int sr = tid >> 2, sc = (tid & 3) << 4;
    int4 r0 = *(const int4*)&Ps[sr * 136 + sc];
    int4 r1 = *(const int4*)&Ps[sr * 136 + sc + 8];
    bf16_t* aout = AO + ((size_t)(b * 2048 + qt * 64 + sr)) * INNER + h * DHEAD + sc;
    *(int4*)aout       = r0;
    *(int4*)(aout + 8) = r1;
  }
}

// ---------- launch ----------
extern "C" void kernel_launch(void* const* d_in, const int* in_sizes, int n_in,
                              void* d_out, int out_size, void* d_ws, size_t ws_size,
                              hipStream_t stream) {
  const float* x   = (const float*)d_in[0];
  const float* ctx = (const float*)d_in[1];
  const float* Wq  = (const float*)d_in[2];
  const float* Wk  = (const float*)d_in[3];
  const float* Wv  = (const float*)d_in[4];
  const float* Wo  = (const float*)d_in[5];
  const float* bo  = (const float*)d_in[6];
  float* out = (float*)d_out;

  char* ws = (char*)d_ws;
  const size_t MB = 1048576;
  bf16_t* WqT = (bf16_t*)(ws + 0 * MB);    //  1 MB  [512][1024]
  bf16_t* WkT = (bf16_t*)(ws + 1 * MB);    //  1 MB
  bf16_t* WvT = (bf16_t*)(ws + 2 * MB);    //  1 MB
  bf16_t* WoT = (bf16_t*)(ws + 3 * MB);    //  1 MB  [1024][512]
  bf16_t* Qb  = (bf16_t*)(ws + 4 * MB);    //  4 MB  [4096][512] (pre-scaled)
  bf16_t* Kb  = (bf16_t*)(ws + 8 * MB);    //  4 MB  [4096][512]
  bf16_t* Vt  = (bf16_t*)(ws + 12 * MB);   //  4 MB  [16][64][2048]
  bf16_t* AO  = (bf16_t*)(ws + 16 * MB);   //  4 MB  [4096][512]

  pre_w_k<<<512, 256, 0, stream>>>(Wq, Wk, Wv, Wo, WqT, WkT, WvT, WoT);
  gemm_qkv_k<<<384, 256, 0, stream>>>(x, ctx, WqT, WkT, WvT, Qb, Kb, Vt);
  attn_k<<<512, 256, 0, stream>>>(Qb, Kb, Vt, AO);
  gemm_out_k<<<512, 256, 0, stream>>>(AO, WoT, bo, out);
}

// Round 12
// 159.302 us; speedup vs baseline: 3.6688x; 1.0179x over previous
//
#include <hip/hip_runtime.h>
#include <math.h>

// ---------- types ----------
typedef __bf16 bf16_t;
typedef __bf16 bf16x8 __attribute__((ext_vector_type(8)));
typedef __bf16 bf16x4 __attribute__((ext_vector_type(4)));
typedef float  f32x4  __attribute__((ext_vector_type(4)));

#define MFMA16(a, b, c) __builtin_amdgcn_mfma_f32_16x16x32_bf16((a), (b), (c), 0, 0, 0)

// B=2, N=M=2048, QUERY_DIM=CONTEXT_DIM=1024, HEADS=8, DIM_HEAD=64, INNER=512
#define INNER   512
#define DHEAD   64
// SCALE * log2(e): Q pre-scaled so softmax runs in exp2 domain
#define QSCALE  0.18033688f

// direct HBM -> LDS, 16 B per lane; LDS dest = wave-uniform base + lane*16
__device__ __forceinline__ void g2l(const bf16_t* g, bf16_t* l) {
  __builtin_amdgcn_global_load_lds(
      (const __attribute__((address_space(1))) unsigned int*)g,
      (__attribute__((address_space(3))) unsigned int*)l, 16, 0, 0);
}

#define SBAR0() __builtin_amdgcn_sched_barrier(0)

// ---------- weight transpose+convert ----------
__global__ __launch_bounds__(256) void pre_w_k(const float* __restrict__ Wq,
                                               const float* __restrict__ Wk,
                                               const float* __restrict__ Wv,
                                               const float* __restrict__ Wo,
                                               bf16_t* __restrict__ WqT,
                                               bf16_t* __restrict__ WkT,
                                               bf16_t* __restrict__ WvT,
                                               bf16_t* __restrict__ WoT) {
  __shared__ float tile[64][65];
  int t = blockIdx.x;               // 0..511, 4 matrices x 128 tiles
  int z = t >> 7, bid = t & 127;
  const float* W; bf16_t* WT; int K, N;
  if (z == 0)      { W = Wq; WT = WqT; K = 1024; N = 512; }
  else if (z == 1) { W = Wk; WT = WkT; K = 1024; N = 512; }
  else if (z == 2) { W = Wv; WT = WvT; K = 1024; N = 512; }
  else             { W = Wo; WT = WoT; K = 512;  N = 1024; }
  int tK = K >> 6;
  int kt = bid % tK, nt = bid / tK;
  int k0 = kt << 6, n0 = nt << 6;
  for (int idx = threadIdx.x; idx < 4096; idx += 256) {
    int r = idx >> 6, c = idx & 63;
    tile[r][c] = W[(size_t)(k0 + r) * N + n0 + c];
  }
  __syncthreads();
  for (int idx = threadIdx.x; idx < 4096; idx += 256) {
    int r = idx >> 6, c = idx & 63;
    WT[(size_t)(n0 + r) * K + k0 + c] = (bf16_t)tile[c][r];
  }
}

// ---------- qkv GEMM core: (MI*32)x128 tile, BK=64, counted-vmcnt pipeline ----------
// A = fp32 (x/ctx), reg-staged depth-2 (ping-pong pA0/pA1, static indexing);
// B = bf16 W^T via global_load_lds (pre-swizzled source).
// Per-wave (4 + 2*MI) vmem ops/step; ISSUE ORDER IS THE CORRECTNESS LEDGER:
// B g2l MUST issue before the A loads (round-11 failure: scheduler permuted
// them across co-compiled template instantiations -> top vmcnt drained A
// instead of B -> MFMA read an unlanded B tile). sched_barrier(0) pins the
// order at every ledger boundary.
//   top:  vmcnt(2*MI)   = B(kc) landed; A(kc+1) [2*MI newer] stays in flight
//   tail: vmcnt(2*MI+4) = A(kc+1) landed; B(kc+1)+A(kc+2) stay in flight
// K-indices wrap on the tail (dummy loads into dead buffers keep counts uniform).
#define QKV_STEP(kc, CURA, NXTA, CURB, NXTB, PRC, PRF)                           \
  {                                                                              \
    asm volatile("s_waitcnt vmcnt(%c0) lgkmcnt(0)" :: "i"(2 * MI) : "memory");   \
    __builtin_amdgcn_s_barrier();                                                \
    SBAR0();                                                                     \
    {                                                                            \
      const int k0b = (((kc) + 1) & (KT - 1)) * 64;                              \
      _Pragma("unroll")                                                          \
      for (int p = 0; p < 4; ++p)                                                \
        g2l(gb + (size_t)(p * 8) * K + k0b, lB + (NXTB) + p * 512);              \
    }                                                                            \
    SBAR0();   /* pin: B g2l issued before A loads (vmcnt ledger) */             \
    {                                                                            \
      const int k0a = (((kc) + 2) & (KT - 1)) * 64;                              \
      _Pragma("unroll")                                                          \
      for (int p = 0; p < MI; ++p) {                                             \
        const float* s_ = ga + (size_t)(p * 8) * K + k0a;                        \
        PRF[2 * p]     = *(const f32x4*)s_;                                      \
        PRF[2 * p + 1] = *(const f32x4*)(s_ + 4);                                \
      }                                                                          \
    }                                                                            \
    SBAR0();   /* pin: A loads issued before MFMA cluster */                     \
    _Pragma("unroll")                                                            \
    for (int ks = 0; ks < 2; ++ks) {                                             \
      const int phys = ((ks * 4 + quad) ^ (l16 & 7)) << 3;                       \
      bf16x8 af[MI], bfr[4];                                                     \
      _Pragma("unroll")                                                          \
      for (int i = 0; i < MI; ++i)                                               \
        af[i] = *(const bf16x8*)&As[(CURA) + (mrow + i * 16 + l16) * 64 + phys]; \
      _Pragma("unroll")                                                          \
      for (int j = 0; j < 4; ++j)                                                \
        bfr[j] = *(const bf16x8*)&Bs[(CURB) + (ncol + j * 16 + l16) * 64 + phys];\
      _Pragma("unroll")                                                          \
      for (int i = 0; i < MI; ++i)                                               \
        _Pragma("unroll")                                                        \
        for (int j = 0; j < 4; ++j)                                              \
          acc[i][j] = MFMA16(af[i], bfr[j], acc[i][j]);                          \
    }                                                                            \
    asm volatile("s_waitcnt vmcnt(%c0)" :: "i"(2 * MI + 4) : "memory");          \
    SBAR0();                                                                     \
    _Pragma("unroll")                                                            \
    for (int p = 0; p < MI; ++p) {                                               \
      bf16x8 h_;                                                                 \
      _Pragma("unroll")                                                          \
      for (int e = 0; e < 4; ++e) {                                              \
        h_[e]     = (bf16_t)PRC[2 * p][e];                                       \
        h_[4 + e] = (bf16_t)PRC[2 * p + 1][e];                                   \
      }                                                                          \
      *(bf16x8*)&lA[(NXTA) + p * 512 + lane * 8] = h_;                           \
    }                                                                            \
  }

// sm: shared 64 KB block (As = first 2*BM*64 elems, Bs = next 2*128*64).
template<int MI>
__device__ __forceinline__ void gemm_qkv_core(bf16_t* sm,
                                              const float* __restrict__ A,
                                              const bf16_t* __restrict__ Bt,
                                              int row0, int n0,
                                              int mode, float scale,
                                              bf16_t* __restrict__ Cb) {
  constexpr int K = 1024, KT = 16;
  constexpr int ABUF = MI * 2048;       // per-buffer A elems (BM*64)
  bf16_t* As = sm;                      // 2*ABUF
  bf16_t* Bs = sm + 2 * ABUF;           // 2*8192
  const int tid = threadIdx.x;
  const int w = tid >> 6, lane = tid & 63, quad = lane >> 4, l16 = lane & 15;
  const int sr8  = lane >> 3;
  const int slog = ((lane & 7) ^ sr8) << 3;
  const float*  ga = A  + (size_t)(row0 + w * (MI * 8) + sr8) * K + slog;
  const bf16_t* gb = Bt + (size_t)(n0   + w * 32 + sr8) * K + slog;
  bf16_t* lA = As + w * MI * 512;
  bf16_t* lB = Bs + w * 2048;

  f32x4 acc[MI][4];
#pragma unroll
  for (int i = 0; i < MI; ++i)
#pragma unroll
    for (int j = 0; j < 4; ++j) acc[i][j] = f32x4{0.f, 0.f, 0.f, 0.f};

  f32x4 pA0[2 * MI], pA1[2 * MI];       // ping-pong A prefetch (static names)
  const int mrow = (w & 1) * (MI * 16), ncol = (w >> 1) << 6;

  // prologue: A(0) direct cvt -> As[0] (loads fully consumed before the ds_write,
  // so they are drained before the first counted wait); B(0) g2l; A(1) -> pA0.
#pragma unroll
  for (int p = 0; p < MI; ++p) {
    const float* s = ga + (size_t)(p * 8) * K;
    f32x4 f0 = *(const f32x4*)s;
    f32x4 f1 = *(const f32x4*)(s + 4);
    bf16x8 h;
#pragma unroll
    for (int e = 0; e < 4; ++e) { h[e] = (bf16_t)f0[e]; h[4 + e] = (bf16_t)f1[e]; }
    *(bf16x8*)&lA[p * 512 + lane * 8] = h;
  }
  SBAR0();
#pragma unroll
  for (int p = 0; p < 4; ++p)
    g2l(gb + (size_t)(p * 8) * K, lB + p * 512);
  SBAR0();   // pin: B(0) g2l issued before A(1) loads (vmcnt ledger)
#pragma unroll
  for (int p = 0; p < MI; ++p) {
    const float* s = ga + (size_t)(p * 8) * K + 64;
    pA0[2 * p]     = *(const f32x4*)s;
    pA0[2 * p + 1] = *(const f32x4*)(s + 4);
  }
  SBAR0();

  for (int kc = 0; kc < KT; kc += 2) {
    QKV_STEP(kc,     0,    ABUF, 0,    8192, pA0, pA1);
    QKV_STEP(kc + 1, ABUF, 0,    8192, 0,    pA1, pA0);
  }

  // epilogue: C/D layout col=l16, row=quad*4+reg
#pragma unroll
  for (int i = 0; i < MI; ++i) {
    int row = row0 + mrow + i * 16 + quad * 4;
#pragma unroll
    for (int j = 0; j < 4; ++j) {
      int col = n0 + ncol + j * 16 + l16;
      if (mode == 2) {
        // scatter to Vt[bh=b*8+h][d][key]: row -> (b,key), col -> (h,d)
        int bb = row >> 11, key = row & 2047;
        int hh = col >> 6,  d   = col & 63;
        bf16x4 v = { (bf16_t)acc[i][j][0], (bf16_t)acc[i][j][1],
                     (bf16_t)acc[i][j][2], (bf16_t)acc[i][j][3] };
        *(bf16x4*)&Cb[((size_t)((bb * 8 + hh) * 64 + d)) * 2048 + key] = v;
      } else {
#pragma unroll
        for (int r = 0; r < 4; ++r)
          Cb[(size_t)(row + r) * 512 + col] = (bf16_t)(acc[i][j][r] * scale);
      }
    }
  }
}

// ---------- QKV: 1-D grid 512 (Q 128 + K 128 @BM=128, V 256 @BM=64) ----------
// 512 = exactly 2 blocks/CU; block c (heavy) pairs with c+256 (light V) on the
// same CU -> balanced makespan. XCD-aware m-grouping keeps each A-panel on one L2.
__global__ __launch_bounds__(256, 2) void gemm_qkv_k(const float* __restrict__ x,
                                                     const float* __restrict__ ctx,
                                                     const bf16_t* __restrict__ WqT,
                                                     const bf16_t* __restrict__ WkT,
                                                     const bf16_t* __restrict__ WvT,
                                                     bf16_t* __restrict__ Qb,
                                                     bf16_t* __restrict__ Kb,
                                                     bf16_t* __restrict__ Vt) {
  __shared__ __align__(16) bf16_t smem[32768];   // 64 KB shared by both paths
  int bid = blockIdx.x;             // 0..511
  if (bid < 256) {                  // Q (0..127) / K (128..255), BM=128
    int z = bid >> 7;
    int t = bid & 127;
    int xcd = t & 7, slot = t >> 3;            // slot 0..15
    int m = (xcd << 2) | (slot >> 2);          // XCD owns m in [4x, 4x+4)
    int n = slot & 3;
    const float* A   = (z == 0) ? x   : ctx;
    const bf16_t* Bt = (z == 0) ? WqT : WkT;
    bf16_t* C        = (z == 0) ? Qb  : Kb;
    float scale      = (z == 0) ? QSCALE : 1.0f;
    gemm_qkv_core<4>(smem, A, Bt, m * 128, n * 128, 0, scale, C);
  } else {                          // V, BM=64, 256 blocks
    int t = bid - 256;              // 0..255
    int xcd = t & 7, slot = t >> 3;            // slot 0..31
    int m = (xcd << 3) | (slot >> 2);          // XCD owns m in [8x, 8x+8)
    int n = slot & 3;
    gemm_qkv_core<2>(smem, ctx, WvT, m * 64, n * 128, 2, 1.0f, Vt);
  }
}

// ---------- generic BMx128 GEMM core (out-proj; bf16 A via g2l) ----------
template<int BM>
__device__ __forceinline__ void gemm_core(const bf16_t* __restrict__ Ab,
                                          const bf16_t* __restrict__ Bt,
                                          int K, int N, int row0, int n0,
                                          float* __restrict__ Cf,
                                          const float* __restrict__ bias) {
  constexpr int MI = BM / 32;
  __shared__ bf16_t As[2 * BM * 64];
  __shared__ bf16_t Bs[2 * 128 * 64];
  const int tid = threadIdx.x;
  const int w = tid >> 6, lane = tid & 63, quad = lane >> 4, l16 = lane & 15;

  const int sr8  = lane >> 3;
  const int slog = ((lane & 7) ^ sr8) << 3;
  const bf16_t* ga = Ab + (size_t)(row0 + w * (BM / 4) + sr8) * K + slog;
  const bf16_t* gb = Bt + (size_t)(n0   + w * 32 + sr8) * K + slog;
  bf16_t* lA = As + w * (BM / 4) * 64;
  bf16_t* lB = Bs + w * 2048;

  f32x4 acc[MI][4];
#pragma unroll
  for (int i = 0; i < MI; ++i)
#pragma unroll
    for (int j = 0; j < 4; ++j) acc[i][j] = f32x4{0.f, 0.f, 0.f, 0.f};

  const int mrow = (w & 1) * (BM / 2), ncol = (w >> 1) << 6;
  const int KT = K >> 6;

#pragma unroll
  for (int p = 0; p < MI; ++p)
    g2l(ga + (size_t)(p * 8) * K, lA + p * 512);
#pragma unroll
  for (int p = 0; p < 4; ++p)
    g2l(gb + (size_t)(p * 8) * K, lB + p * 512);

  for (int kc = 0; kc < KT; ++kc) {
    const int curA = (kc & 1) * (BM * 64), nxtA = ((kc + 1) & 1) * (BM * 64);
    const int curB = (kc & 1) * 8192,      nxtB = ((kc + 1) & 1) * 8192;
    __syncthreads();
    if (kc + 1 < KT) {
      const int k0 = (kc + 1) * 64;
#pragma unroll
      for (int p = 0; p < MI; ++p)
        g2l(ga + (size_t)(p * 8) * K + k0, lA + nxtA + p * 512);
#pragma unroll
      for (int p = 0; p < 4; ++p)
        g2l(gb + (size_t)(p * 8) * K + k0, lB + nxtB + p * 512);
    }
#pragma unroll
    for (int ks = 0; ks < 2; ++ks) {
      const int phys = ((ks * 4 + quad) ^ (l16 & 7)) << 3;
      bf16x8 af[MI], bfr[4];
#pragma unroll
      for (int i = 0; i < MI; ++i)
        af[i] = *(const bf16x8*)&As[curA + (mrow + i * 16 + l16) * 64 + phys];
#pragma unroll
      for (int j = 0; j < 4; ++j)
        bfr[j] = *(const bf16x8*)&Bs[curB + (ncol + j * 16 + l16) * 64 + phys];
#pragma unroll
      for (int i = 0; i < MI; ++i)
#pragma unroll
        for (int j = 0; j < 4; ++j)
          acc[i][j] = MFMA16(af[i], bfr[j], acc[i][j]);
    }
  }

#pragma unroll
  for (int i = 0; i < MI; ++i) {
    int row = row0 + mrow + i * 16 + quad * 4;
#pragma unroll
    for (int j = 0; j < 4; ++j) {
      int col = n0 + ncol + j * 16 + l16;
#pragma unroll
      for (int r = 0; r < 4; ++r)
        Cf[(size_t)(row + r) * N + col] = acc[i][j][r] + bias[col];
    }
  }
}

// ---------- out-proj: 1-D grid 512, XCD-aware m-grouping ----------
__global__ __launch_bounds__(256, 2) void gemm_out_k(const bf16_t* __restrict__ AO,
                                                     const bf16_t* __restrict__ WoT,
                                                     const float* __restrict__ bo,
                                                     float* __restrict__ out) {
  int bid = blockIdx.x;             // 0..511
  int xcd  = bid & 7;
  int slot = bid >> 3;              // 0..63
  int m = (xcd << 3) | (slot >> 3); // 0..63
  int n = slot & 7;
  gemm_core<64>(AO, WoT, 512, 1024, m * 64, n * 128, out, bo);
}

// ---------- flash attention: 1-D grid 512, XCD-aware bh-grouping ----------
// Counted mid-wait: V(kt) issued FIRST (pinned by sched_barrier), K(kt+1)
// second; mid waits vmcnt(4) lgkmcnt(0) -> V landed, K-prefetch stays in
// flight across the mid barrier (covered by softmax+PV). K prefetch is
// unconditional with wrap (kt=15 writes a dead buffer) to keep counts uniform.
__global__ __launch_bounds__(256, 2) void attn_k(const bf16_t* __restrict__ Qb,
                                                 const bf16_t* __restrict__ Kb,
                                                 const bf16_t* __restrict__ Vt,
                                                 bf16_t* __restrict__ AO) {
  const int tid = threadIdx.x;
  const int w = tid >> 6, lane = tid & 63, quad = lane >> 4, l16 = lane & 15;
  int bid = blockIdx.x;             // 0..511
  int xcd  = bid & 7;
  int slot = bid >> 3;              // 0..63
  const int qt = slot & 31;         // 0..31
  const int bh = (xcd << 1) | (slot >> 5);   // 0..15
  const int b = bh >> 3, h = bh & 7;

  __shared__ bf16_t Ks[2 * 128 * 64];  // [buf][key][d] rows 128 B, swizzle r&7
  __shared__ bf16_t Vs[64 * 128];      // [d][key]      rows 256 B, swizzle r&15
  __shared__ bf16_t Ps[64 * 136];      // [q][key]      padded, wave-private rows

  const int qrow = b * 2048 + qt * 64 + w * 16 + l16;
  const bf16_t* qptr = Qb + (size_t)qrow * INNER + h * DHEAD;
  bf16x8 bq[2];
  bq[0] = *(const bf16x8*)(qptr + quad * 8);
  bq[1] = *(const bf16x8*)(qptr + 32 + quad * 8);

  f32x4 o[4];
#pragma unroll
  for (int dt = 0; dt < 4; ++dt) o[dt] = f32x4{0.f, 0.f, 0.f, 0.f};
  float m_s = -__builtin_inff(), l_s = 0.f;

  const bf16_t* kbase  = Kb + ((size_t)b * 2048) * INNER + h * DHEAD;
  const bf16_t* vtbase = Vt + ((size_t)bh * 64) * 2048;

  const int krow = lane >> 3;
  const int kcol = ((lane & 7) ^ (lane >> 3)) << 3;
  const int vrow = lane >> 4;

#pragma unroll
  for (int p = 0; p < 4; ++p)
    g2l(kbase + (size_t)(w * 32 + p * 8 + krow) * INNER + kcol,
        &Ks[w * 2048 + p * 512]);

  for (int kt = 0; kt < 16; ++kt) {
    const int cur = (kt & 1) * 8192, nxt = ((kt + 1) & 1) * 8192;
    __syncthreads();                 // top: drains K(kt) (full-iter cover)
    // V(kt) first (waited at mid), K(kt+1) second (flies across mid barrier).
#pragma unroll
    for (int p = 0; p < 4; ++p) {
      int vlog = ((lane & 15) ^ ((p * 4 + vrow) & 15)) << 3;
      g2l(vtbase + (size_t)(w * 16 + p * 4 + vrow) * 2048 + kt * 128 + vlog,
          &Vs[w * 2048 + p * 512]);
    }
    SBAR0();   // pin: V g2l issued before K g2l (vmcnt ledger)
    {
      const int ktn = (kt + 1) & 15;  // wrap: kt=15 writes dead buffer
#pragma unroll
      for (int p = 0; p < 4; ++p)
        g2l(kbase + (size_t)(ktn * 128 + w * 32 + p * 8 + krow) * INNER + kcol,
            &Ks[nxt + w * 2048 + p * 512]);
    }
    SBAR0();

    f32x4 s[8];
#pragma unroll
    for (int jt = 0; jt < 8; ++jt) s[jt] = f32x4{0.f, 0.f, 0.f, 0.f};
    __builtin_amdgcn_s_setprio(1);      // T5: favor MFMA wave on CU scheduler
#pragma unroll
    for (int jt = 0; jt < 8; ++jt) {
#pragma unroll
      for (int ks = 0; ks < 2; ++ks) {
        int phys = ((ks * 4 + quad) ^ (l16 & 7)) << 3;
        bf16x8 ak = *(const bf16x8*)&Ks[cur + (jt * 16 + l16) * 64 + phys];
        s[jt] = MFMA16(ak, bq[ks], s[jt]);
      }
    }
    __builtin_amdgcn_s_setprio(0);

    float mx = -__builtin_inff();
#pragma unroll
    for (int jt = 0; jt < 8; ++jt) {
      float a = fmaxf(fmaxf(s[jt][0], s[jt][1]), fmaxf(s[jt][2], s[jt][3]));
      mx = fmaxf(mx, a);
    }
    mx = fmaxf(mx, __shfl_xor(mx, 16, 64));
    mx = fmaxf(mx, __shfl_xor(mx, 32, 64));
    float mnew = fmaxf(m_s, mx);
    float alpha = __builtin_amdgcn_exp2f(m_s - mnew);
    float rs = 0.f;
#pragma unroll
    for (int jt = 0; jt < 8; ++jt) {
#pragma unroll
      for (int r = 0; r < 4; ++r) {
        float p = __builtin_amdgcn_exp2f(s[jt][r] - mnew);
        s[jt][r] = p;
        rs += p;
      }
    }
    rs += __shfl_xor(rs, 16, 64);
    rs += __shfl_xor(rs, 32, 64);
    l_s = l_s * alpha + rs;
    m_s = mnew;
#pragma unroll
    for (int dt = 0; dt < 4; ++dt) o[dt] *= alpha;

#pragma unroll
    for (int jt = 0; jt < 8; ++jt) {
      bf16x4 pk = { (bf16_t)s[jt][0], (bf16_t)s[jt][1],
                    (bf16_t)s[jt][2], (bf16_t)s[jt][3] };
      *(bf16x4*)&Ps[(w * 16 + l16) * 136 + jt * 16 + quad * 4] = pk;
    }

    // mid: V(kt) landed (4 oldest of 8 outstanding); Ps writes visible
    asm volatile("s_waitcnt vmcnt(4) lgkmcnt(0)" ::: "memory");
    __builtin_amdgcn_s_barrier();
    SBAR0();

    __builtin_amdgcn_s_setprio(1);
#pragma unroll
    for (int kc = 0; kc < 4; ++kc) {
      bf16x8 bp = *(const bf16x8*)&Ps[(w * 16 + l16) * 136 + kc * 32 + quad * 8];
#pragma unroll
      for (int dt = 0; dt < 4; ++dt) {
        int phys = ((kc * 4 + quad) ^ l16) << 3;
        bf16x8 av = *(const bf16x8*)&Vs[(dt * 16 + l16) * 128 + phys];
        o[dt] = MFMA16(av, bp, o[dt]);
      }
    }
    __builtin_amdgcn_s_setprio(0);
  }

  float inv = 1.0f / l_s;
#pragma unroll
  for (int dt = 0; dt < 4; ++dt) {
    bf16x4 ov = { (bf16_t)(o[dt][0] * inv), (bf16_t)(o[dt][1] * inv),
                  (bf16_t)(o[dt][2] * inv), (bf16_t)(o[dt][3] * inv) };
    *(bf16x4*)&Ps[(w * 16 + l16) * 136 + dt * 16 + quad * 4] = ov;
  }
  __syncthreads();
  {
    int sr = tid >> 2, sc = (tid & 3) << 4;
    int4 r0 = *(const int4*)&Ps[sr * 136 + sc];
    int4 r1 = *(const int4*)&Ps[sr * 136 + sc + 8];
    bf16_t* aout = AO + ((size_t)(b * 2048 + qt * 64 + sr)) * INNER + h * DHEAD + sc;
    *(int4*)aout       = r0;
    *(int4*)(aout + 8) = r1;
  }
}

// ---------- launch ----------
extern "C" void kernel_launch(void* const* d_in, const int* in_sizes, int n_in,
                              void* d_out, int out_size, void* d_ws, size_t ws_size,
                              hipStream_t stream) {
  const float* x   = (const float*)d_in[0];
  const float* ctx = (const float*)d_in[1];
  const float* Wq  = (const float*)d_in[2];
  const float* Wk  = (const float*)d_in[3];
  const float* Wv  = (const float*)d_in[4];
  const float* Wo  = (const float*)d_in[5];
  const float* bo  = (const float*)d_in[6];
  float* out = (float*)d_out;

  char* ws = (char*)d_ws;
  const size_t MB = 1048576;
  bf16_t* WqT = (bf16_t*)(ws + 0 * MB);    //  1 MB  [512][1024]
  bf16_t* WkT = (bf16_t*)(ws + 1 * MB);    //  1 MB
  bf16_t* WvT = (bf16_t*)(ws + 2 * MB);    //  1 MB
  bf16_t* WoT = (bf16_t*)(ws + 3 * MB);    //  1 MB  [1024][512]
  bf16_t* Qb  = (bf16_t*)(ws + 4 * MB);    //  4 MB  [4096][512] (pre-scaled)
  bf16_t* Kb  = (bf16_t*)(ws + 8 * MB);    //  4 MB  [4096][512]
  bf16_t* Vt  = (bf16_t*)(ws + 12 * MB);   //  4 MB  [16][64][2048]
  bf16_t* AO  = (bf16_t*)(ws + 16 * MB);   //  4 MB  [4096][512]

  pre_w_k<<<512, 256, 0, stream>>>(Wq, Wk, Wv, Wo, WqT, WkT, WvT, WoT);
  gemm_qkv_k<<<512, 256, 0, stream>>>(x, ctx, WqT, WkT, WvT, Qb, Kb, Vt);
  attn_k<<<512, 256, 0, stream>>>(Qb, Kb, Vt, AO);
  gemm_out_k<<<512, 256, 0, stream>>>(AO, WoT, bo, out);
}

// Round 13
// 158.926 us; speedup vs baseline: 3.6774x; 1.0024x over previous
//
#include <hip/hip_runtime.h>
#include <math.h>

// ---------- types ----------
typedef __bf16 bf16_t;
typedef __bf16 bf16x8 __attribute__((ext_vector_type(8)));
typedef __bf16 bf16x4 __attribute__((ext_vector_type(4)));
typedef float  f32x4  __attribute__((ext_vector_type(4)));

#define MFMA16(a, b, c) __builtin_amdgcn_mfma_f32_16x16x32_bf16((a), (b), (c), 0, 0, 0)

// B=2, N=M=2048, QUERY_DIM=CONTEXT_DIM=1024, HEADS=8, DIM_HEAD=64, INNER=512
#define INNER   512
#define DHEAD   64
// SCALE * log2(e): Q pre-scaled so softmax runs in exp2 domain
#define QSCALE  0.18033688f

// direct HBM -> LDS, 16 B per lane; LDS dest = wave-uniform base + lane*16
__device__ __forceinline__ void g2l(const bf16_t* g, bf16_t* l) {
  __builtin_amdgcn_global_load_lds(
      (const __attribute__((address_space(1))) unsigned int*)g,
      (__attribute__((address_space(3))) unsigned int*)l, 16, 0, 0);
}

#define SBAR0() __builtin_amdgcn_sched_barrier(0)

// ---------- weight transpose+convert ----------
__global__ __launch_bounds__(256) void pre_w_k(const float* __restrict__ Wq,
                                               const float* __restrict__ Wk,
                                               const float* __restrict__ Wv,
                                               const float* __restrict__ Wo,
                                               bf16_t* __restrict__ WqT,
                                               bf16_t* __restrict__ WkT,
                                               bf16_t* __restrict__ WvT,
                                               bf16_t* __restrict__ WoT) {
  __shared__ float tile[64][65];
  int t = blockIdx.x;               // 0..511, 4 matrices x 128 tiles
  int z = t >> 7, bid = t & 127;
  const float* W; bf16_t* WT; int K, N;
  if (z == 0)      { W = Wq; WT = WqT; K = 1024; N = 512; }
  else if (z == 1) { W = Wk; WT = WkT; K = 1024; N = 512; }
  else if (z == 2) { W = Wv; WT = WvT; K = 1024; N = 512; }
  else             { W = Wo; WT = WoT; K = 512;  N = 1024; }
  int tK = K >> 6;
  int kt = bid % tK, nt = bid / tK;
  int k0 = kt << 6, n0 = nt << 6;
  for (int idx = threadIdx.x; idx < 4096; idx += 256) {
    int r = idx >> 6, c = idx & 63;
    tile[r][c] = W[(size_t)(k0 + r) * N + n0 + c];
  }
  __syncthreads();
  for (int idx = threadIdx.x; idx < 4096; idx += 256) {
    int r = idx >> 6, c = idx & 63;
    WT[(size_t)(n0 + r) * K + k0 + c] = (bf16_t)tile[c][r];
  }
}

// ---------- qkv GEMM core: (MI*32)x128 tile, BK=64, counted-vmcnt pipeline ----------
// A = fp32 (x/ctx), reg-staged depth-2 (ping-pong pA0/pA1, static indexing);
// B = bf16 W^T via global_load_lds (pre-swizzled source).
// ISSUE ORDER IS THE CORRECTNESS LEDGER (round-11 lesson): B g2l before A loads,
// pinned with sched_barrier(0) at every ledger boundary.
//   top:  vmcnt(2*MI)   = B(kc) landed; A(kc+1) [2*MI newer] stays in flight
//   tail: vmcnt(2*MI+4) = A(kc+1) landed; B(kc+1)+A(kc+2) stay in flight
// K-indices wrap on the tail (dummy loads into dead buffers keep counts uniform).
#define QKV_STEP(kc, CURA, NXTA, CURB, NXTB, PRC, PRF)                           \
  {                                                                              \
    asm volatile("s_waitcnt vmcnt(%c0) lgkmcnt(0)" :: "i"(2 * MI) : "memory");   \
    __builtin_amdgcn_s_barrier();                                                \
    SBAR0();                                                                     \
    {                                                                            \
      const int k0b = (((kc) + 1) & (KT - 1)) * 64;                              \
      _Pragma("unroll")                                                          \
      for (int p = 0; p < 4; ++p)                                                \
        g2l(gb + (size_t)(p * 8) * K + k0b, lB + (NXTB) + p * 512);              \
    }                                                                            \
    SBAR0();   /* pin: B g2l issued before A loads (vmcnt ledger) */             \
    {                                                                            \
      const int k0a = (((kc) + 2) & (KT - 1)) * 64;                              \
      _Pragma("unroll")                                                          \
      for (int p = 0; p < MI; ++p) {                                             \
        const float* s_ = ga + (size_t)(p * 8) * K + k0a;                        \
        PRF[2 * p]     = *(const f32x4*)s_;                                      \
        PRF[2 * p + 1] = *(const f32x4*)(s_ + 4);                                \
      }                                                                          \
    }                                                                            \
    SBAR0();   /* pin: A loads issued before MFMA cluster */                     \
    _Pragma("unroll")                                                            \
    for (int ks = 0; ks < 2; ++ks) {                                             \
      const int phys = ((ks * 4 + quad) ^ (l16 & 7)) << 3;                       \
      bf16x8 af[MI], bfr[4];                                                     \
      _Pragma("unroll")                                                          \
      for (int i = 0; i < MI; ++i)                                               \
        af[i] = *(const bf16x8*)&As[(CURA) + (mrow + i * 16 + l16) * 64 + phys]; \
      _Pragma("unroll")                                                          \
      for (int j = 0; j < 4; ++j)                                                \
        bfr[j] = *(const bf16x8*)&Bs[(CURB) + (ncol + j * 16 + l16) * 64 + phys];\
      _Pragma("unroll")                                                          \
      for (int i = 0; i < MI; ++i)                                               \
        _Pragma("unroll")                                                        \
        for (int j = 0; j < 4; ++j)                                              \
          acc[i][j] = MFMA16(af[i], bfr[j], acc[i][j]);                          \
    }                                                                            \
    asm volatile("s_waitcnt vmcnt(%c0)" :: "i"(2 * MI + 4) : "memory");          \
    SBAR0();                                                                     \
    _Pragma("unroll")                                                            \
    for (int p = 0; p < MI; ++p) {                                               \
      bf16x8 h_;                                                                 \
      _Pragma("unroll")                                                          \
      for (int e = 0; e < 4; ++e) {                                              \
        h_[e]     = (bf16_t)PRC[2 * p][e];                                       \
        h_[4 + e] = (bf16_t)PRC[2 * p + 1][e];                                   \
      }                                                                          \
      *(bf16x8*)&lA[(NXTA) + p * 512 + lane * 8] = h_;                           \
    }                                                                            \
  }

// sm: shared 64 KB block (As = first 2*BM*64 elems, Bs = next 2*128*64).
template<int MI>
__device__ __forceinline__ void gemm_qkv_core(bf16_t* sm,
                                              const float* __restrict__ A,
                                              const bf16_t* __restrict__ Bt,
                                              int row0, int n0,
                                              int mode, float scale,
                                              bf16_t* __restrict__ Cb) {
  constexpr int K = 1024, KT = 16;
  constexpr int ABUF = MI * 2048;       // per-buffer A elems (BM*64)
  bf16_t* As = sm;                      // 2*ABUF
  bf16_t* Bs = sm + 2 * ABUF;           // 2*8192
  const int tid = threadIdx.x;
  const int w = tid >> 6, lane = tid & 63, quad = lane >> 4, l16 = lane & 15;
  const int sr8  = lane >> 3;
  const int slog = ((lane & 7) ^ sr8) << 3;
  const float*  ga = A  + (size_t)(row0 + w * (MI * 8) + sr8) * K + slog;
  const bf16_t* gb = Bt + (size_t)(n0   + w * 32 + sr8) * K + slog;
  bf16_t* lA = As + w * MI * 512;
  bf16_t* lB = Bs + w * 2048;

  f32x4 acc[MI][4];
#pragma unroll
  for (int i = 0; i < MI; ++i)
#pragma unroll
    for (int j = 0; j < 4; ++j) acc[i][j] = f32x4{0.f, 0.f, 0.f, 0.f};

  f32x4 pA0[2 * MI], pA1[2 * MI];       // ping-pong A prefetch (static names)
  const int mrow = (w & 1) * (MI * 16), ncol = (w >> 1) << 6;

  // prologue: A(0) direct cvt -> As[0] (loads fully consumed before ds_write);
  // B(0) g2l; A(1) -> pA0.
#pragma unroll
  for (int p = 0; p < MI; ++p) {
    const float* s = ga + (size_t)(p * 8) * K;
    f32x4 f0 = *(const f32x4*)s;
    f32x4 f1 = *(const f32x4*)(s + 4);
    bf16x8 h;
#pragma unroll
    for (int e = 0; e < 4; ++e) { h[e] = (bf16_t)f0[e]; h[4 + e] = (bf16_t)f1[e]; }
    *(bf16x8*)&lA[p * 512 + lane * 8] = h;
  }
  SBAR0();
#pragma unroll
  for (int p = 0; p < 4; ++p)
    g2l(gb + (size_t)(p * 8) * K, lB + p * 512);
  SBAR0();   // pin: B(0) g2l issued before A(1) loads (vmcnt ledger)
#pragma unroll
  for (int p = 0; p < MI; ++p) {
    const float* s = ga + (size_t)(p * 8) * K + 64;
    pA0[2 * p]     = *(const f32x4*)s;
    pA0[2 * p + 1] = *(const f32x4*)(s + 4);
  }
  SBAR0();

  for (int kc = 0; kc < KT; kc += 2) {
    QKV_STEP(kc,     0,    ABUF, 0,    8192, pA0, pA1);
    QKV_STEP(kc + 1, ABUF, 0,    8192, 0,    pA1, pA0);
  }

  // epilogue: C/D layout col=l16, row=quad*4+reg
#pragma unroll
  for (int i = 0; i < MI; ++i) {
    int row = row0 + mrow + i * 16 + quad * 4;
#pragma unroll
    for (int j = 0; j < 4; ++j) {
      int col = n0 + ncol + j * 16 + l16;
      if (mode == 2) {
        // scatter to Vt[bh=b*8+h][d][key]: row -> (b,key), col -> (h,d)
        int bb = row >> 11, key = row & 2047;
        int hh = col >> 6,  d   = col & 63;
        bf16x4 v = { (bf16_t)acc[i][j][0], (bf16_t)acc[i][j][1],
                     (bf16_t)acc[i][j][2], (bf16_t)acc[i][j][3] };
        *(bf16x4*)&Cb[((size_t)((bb * 8 + hh) * 64 + d)) * 2048 + key] = v;
      } else {
#pragma unroll
        for (int r = 0; r < 4; ++r)
          Cb[(size_t)(row + r) * 512 + col] = (bf16_t)(acc[i][j][r] * scale);
      }
    }
  }
}

// ---------- QKV: 1-D grid 512 (Q 128 + K 128 @BM=128, V 256 @BM=64) ----------
// 512 = exactly 2 blocks/CU; block c (heavy) pairs with c+256 (light V) on the
// same CU -> balanced makespan. XCD-aware m-grouping keeps each A-panel on one L2.
__global__ __launch_bounds__(256, 2) void gemm_qkv_k(const float* __restrict__ x,
                                                     const float* __restrict__ ctx,
                                                     const bf16_t* __restrict__ WqT,
                                                     const bf16_t* __restrict__ WkT,
                                                     const bf16_t* __restrict__ WvT,
                                                     bf16_t* __restrict__ Qb,
                                                     bf16_t* __restrict__ Kb,
                                                     bf16_t* __restrict__ Vt) {
  __shared__ __align__(16) bf16_t smem[32768];   // 64 KB shared by both paths
  int bid = blockIdx.x;             // 0..511
  if (bid < 256) {                  // Q (0..127) / K (128..255), BM=128
    int z = bid >> 7;
    int t = bid & 127;
    int xcd = t & 7, slot = t >> 3;            // slot 0..15
    int m = (xcd << 2) | (slot >> 2);          // XCD owns m in [4x, 4x+4)
    int n = slot & 3;
    const float* A   = (z == 0) ? x   : ctx;
    const bf16_t* Bt = (z == 0) ? WqT : WkT;
    bf16_t* C        = (z == 0) ? Qb  : Kb;
    float scale      = (z == 0) ? QSCALE : 1.0f;
    gemm_qkv_core<4>(smem, A, Bt, m * 128, n * 128, 0, scale, C);
  } else {                          // V, BM=64, 256 blocks
    int t = bid - 256;              // 0..255
    int xcd = t & 7, slot = t >> 3;            // slot 0..31
    int m = (xcd << 3) | (slot >> 2);          // XCD owns m in [8x, 8x+8)
    int n = slot & 3;
    gemm_qkv_core<2>(smem, ctx, WvT, m * 64, n * 128, 2, 1.0f, Vt);
  }
}

// ---------- out-proj core: 64x128 tile, K=512, 3-buffer counted-vmcnt ----------
// Both operands bf16 via g2l; 2-deep prefetch (3 LDS buffers, 72 KB total):
// per-wave 6 g2l/tile (A 2 + B 4, order pinned). Steady state: 12 outstanding;
// top wait vmcnt(6) lgkmcnt(0) drains exactly tile(kc). Tile cover = 2 full
// steps (~1280 cyc > 900 cyc HBM latency) vs 1 step with the old __syncthreads
// structure. Wrap-around dummy issues (kc+2 >= KT) keep counts uniform; they
// overwrite buffers whose last reader finished before the preceding barrier.
__device__ __forceinline__ void gemm_out_core(const bf16_t* __restrict__ Ab,
                                              const bf16_t* __restrict__ Bt,
                                              int row0, int n0,
                                              float* __restrict__ Cf,
                                              const float* __restrict__ bias) {
  constexpr int K = 512, KT = 8;
  __shared__ bf16_t As[3 * 4096];   // 3 bufs x 64x64  (24 KB)
  __shared__ bf16_t Bs[3 * 8192];   // 3 bufs x 128x64 (48 KB)
  const int tid = threadIdx.x;
  const int w = tid >> 6, lane = tid & 63, quad = lane >> 4, l16 = lane & 15;
  const int sr8  = lane >> 3;
  const int slog = ((lane & 7) ^ sr8) << 3;
  const bf16_t* ga = Ab + (size_t)(row0 + w * 16 + sr8) * K + slog;
  const bf16_t* gb = Bt + (size_t)(n0   + w * 32 + sr8) * K + slog;
  bf16_t* lA = As + w * 1024;       // + buf*4096 + p*512
  bf16_t* lB = Bs + w * 2048;       // + buf*8192 + p*512

  f32x4 acc[2][4];
#pragma unroll
  for (int i = 0; i < 2; ++i)
#pragma unroll
    for (int j = 0; j < 4; ++j) acc[i][j] = f32x4{0.f, 0.f, 0.f, 0.f};

  const int mrow = (w & 1) * 32, ncol = (w >> 1) << 6;

  // prologue: issue T0 then T1 (A-then-B within each tile, all pinned)
#pragma unroll
  for (int t = 0; t < 2; ++t) {
#pragma unroll
    for (int p = 0; p < 2; ++p)
      g2l(ga + (size_t)(p * 8) * K + t * 64, lA + t * 4096 + p * 512);
    SBAR0();
#pragma unroll
    for (int p = 0; p < 4; ++p)
      g2l(gb + (size_t)(p * 8) * K + t * 64, lB + t * 8192 + p * 512);
    SBAR0();
  }

  int rbuf = 0;                     // = kc % 3
  int wbuf = 2;                     // = (kc+2) % 3
  for (int kc = 0; kc < KT; ++kc) {
    asm volatile("s_waitcnt vmcnt(6) lgkmcnt(0)" ::: "memory");  // T(kc) landed
    __builtin_amdgcn_s_barrier();
    SBAR0();
    {
      const int kn = ((kc + 2) & (KT - 1)) * 64;  // wrap: dummy into dead buffer
#pragma unroll
      for (int p = 0; p < 2; ++p)
        g2l(ga + (size_t)(p * 8) * K + kn, lA + wbuf * 4096 + p * 512);
      SBAR0();   // pin: A before B (tile-granular vmcnt ledger)
#pragma unroll
      for (int p = 0; p < 4; ++p)
        g2l(gb + (size_t)(p * 8) * K + kn, lB + wbuf * 8192 + p * 512);
      SBAR0();
    }
    const int cA = rbuf * 4096, cB = rbuf * 8192;
#pragma unroll
    for (int ks = 0; ks < 2; ++ks) {
      const int phys = ((ks * 4 + quad) ^ (l16 & 7)) << 3;
      bf16x8 af[2], bfr[4];
#pragma unroll
      for (int i = 0; i < 2; ++i)
        af[i] = *(const bf16x8*)&As[cA + (mrow + i * 16 + l16) * 64 + phys];
#pragma unroll
      for (int j = 0; j < 4; ++j)
        bfr[j] = *(const bf16x8*)&Bs[cB + (ncol + j * 16 + l16) * 64 + phys];
#pragma unroll
      for (int i = 0; i < 2; ++i)
#pragma unroll
        for (int j = 0; j < 4; ++j)
          acc[i][j] = MFMA16(af[i], bfr[j], acc[i][j]);
    }
    rbuf = (rbuf == 2) ? 0 : rbuf + 1;
    wbuf = (wbuf == 2) ? 0 : wbuf + 1;
  }

#pragma unroll
  for (int i = 0; i < 2; ++i) {
    int row = row0 + mrow + i * 16 + quad * 4;
#pragma unroll
    for (int j = 0; j < 4; ++j) {
      int col = n0 + ncol + j * 16 + l16;
#pragma unroll
      for (int r = 0; r < 4; ++r)
        Cf[(size_t)(row + r) * 1024 + col] = acc[i][j][r] + bias[col];
    }
  }
}

// ---------- out-proj: 1-D grid 512, XCD-aware m-grouping ----------
__global__ __launch_bounds__(256, 2) void gemm_out_k(const bf16_t* __restrict__ AO,
                                                     const bf16_t* __restrict__ WoT,
                                                     const float* __restrict__ bo,
                                                     float* __restrict__ out) {
  int bid = blockIdx.x;             // 0..511
  int xcd  = bid & 7;
  int slot = bid >> 3;              // 0..63
  int m = (xcd << 3) | (slot >> 3); // 0..63
  int n = slot & 7;
  gemm_out_core(AO, WoT, m * 64, n * 128, out, bo);
}

// ---------- flash attention: 1-D grid 512, XCD-aware bh-grouping ----------
// Counted mid-wait: V(kt) issued FIRST (pinned), K(kt+1) second; mid waits
// vmcnt(4) lgkmcnt(0) -> V landed, K-prefetch flies across the mid barrier.
// Defer-max (T13): skip the O/l rescale when the new tile max is within 8
// (exp2 domain) of the running max -- P bounded by 2^8, f32 accum headroom ok.
__global__ __launch_bounds__(256, 2) void attn_k(const bf16_t* __restrict__ Qb,
                                                 const bf16_t* __restrict__ Kb,
                                                 const bf16_t* __restrict__ Vt,
                                                 bf16_t* __restrict__ AO) {
  const int tid = threadIdx.x;
  const int w = tid >> 6, lane = tid & 63, quad = lane >> 4, l16 = lane & 15;
  int bid = blockIdx.x;             // 0..511
  int xcd  = bid & 7;
  int slot = bid >> 3;              // 0..63
  const int qt = slot & 31;         // 0..31
  const int bh = (xcd << 1) | (slot >> 5);   // 0..15
  const int b = bh >> 3, h = bh & 7;

  __shared__ bf16_t Ks[2 * 128 * 64];  // [buf][key][d] rows 128 B, swizzle r&7
  __shared__ bf16_t Vs[64 * 128];      // [d][key]      rows 256 B, swizzle r&15
  __shared__ bf16_t Ps[64 * 136];      // [q][key]      padded, wave-private rows

  const int qrow = b * 2048 + qt * 64 + w * 16 + l16;
  const bf16_t* qptr = Qb + (size_t)qrow * INNER + h * DHEAD;
  bf16x8 bq[2];
  bq[0] = *(const bf16x8*)(qptr + quad * 8);
  bq[1] = *(const bf16x8*)(qptr + 32 + quad * 8);

  f32x4 o[4];
#pragma unroll
  for (int dt = 0; dt < 4; ++dt) o[dt] = f32x4{0.f, 0.f, 0.f, 0.f};
  float m_s = -__builtin_inff(), l_s = 0.f;

  const bf16_t* kbase  = Kb + ((size_t)b * 2048) * INNER + h * DHEAD;
  const bf16_t* vtbase = Vt + ((size_t)bh * 64) * 2048;

  const int krow = lane >> 3;
  const int kcol = ((lane & 7) ^ (lane >> 3)) << 3;
  const int vrow = lane >> 4;

#pragma unroll
  for (int p = 0; p < 4; ++p)
    g2l(kbase + (size_t)(w * 32 + p * 8 + krow) * INNER + kcol,
        &Ks[w * 2048 + p * 512]);

  for (int kt = 0; kt < 16; ++kt) {
    const int cur = (kt & 1) * 8192, nxt = ((kt + 1) & 1) * 8192;
    __syncthreads();                 // top: drains K(kt) (full-iter cover)
    // V(kt) first (waited at mid), K(kt+1) second (flies across mid barrier).
#pragma unroll
    for (int p = 0; p < 4; ++p) {
      int vlog = ((lane & 15) ^ ((p * 4 + vrow) & 15)) << 3;
      g2l(vtbase + (size_t)(w * 16 + p * 4 + vrow) * 2048 + kt * 128 + vlog,
          &Vs[w * 2048 + p * 512]);
    }
    SBAR0();   // pin: V g2l issued before K g2l (vmcnt ledger)
    {
      const int ktn = (kt + 1) & 15;  // wrap: kt=15 writes dead buffer
#pragma unroll
      for (int p = 0; p < 4; ++p)
        g2l(kbase + (size_t)(ktn * 128 + w * 32 + p * 8 + krow) * INNER + kcol,
            &Ks[nxt + w * 2048 + p * 512]);
    }
    SBAR0();

    f32x4 s[8];
#pragma unroll
    for (int jt = 0; jt < 8; ++jt) s[jt] = f32x4{0.f, 0.f, 0.f, 0.f};
    __builtin_amdgcn_s_setprio(1);      // T5: favor MFMA wave on CU scheduler
#pragma unroll
    for (int jt = 0; jt < 8; ++jt) {
#pragma unroll
      for (int ks = 0; ks < 2; ++ks) {
        int phys = ((ks * 4 + quad) ^ (l16 & 7)) << 3;
        bf16x8 ak = *(const bf16x8*)&Ks[cur + (jt * 16 + l16) * 64 + phys];
        s[jt] = MFMA16(ak, bq[ks], s[jt]);
      }
    }
    __builtin_amdgcn_s_setprio(0);

    float mx = -__builtin_inff();
#pragma unroll
    for (int jt = 0; jt < 8; ++jt) {
      float a = fmaxf(fmaxf(s[jt][0], s[jt][1]), fmaxf(s[jt][2], s[jt][3]));
      mx = fmaxf(mx, a);
    }
    mx = fmaxf(mx, __shfl_xor(mx, 16, 64));
    mx = fmaxf(mx, __shfl_xor(mx, 32, 64));
    // defer-max: only rescale when some row's max grew by > 8 (exp2 units).
    // First iteration: m_s = -inf -> condition false -> rescale path taken.
    if (!__all(mx - m_s <= 8.0f)) {
      float mnew = fmaxf(m_s, mx);
      float alpha = __builtin_amdgcn_exp2f(m_s - mnew);
      l_s *= alpha;
#pragma unroll
      for (int dt = 0; dt < 4; ++dt) o[dt] *= alpha;
      m_s = mnew;
    }
    float rs = 0.f;
#pragma unroll
    for (int jt = 0; jt < 8; ++jt) {
#pragma unroll
      for (int r = 0; r < 4; ++r) {
        float p = __builtin_amdgcn_exp2f(s[jt][r] - m_s);
        s[jt][r] = p;
        rs += p;
      }
    }
    rs += __shfl_xor(rs, 16, 64);
    rs += __shfl_xor(rs, 32, 64);
    l_s += rs;

#pragma unroll
    for (int jt = 0; jt < 8; ++jt) {
      bf16x4 pk = { (bf16_t)s[jt][0], (bf16_t)s[jt][1],
                    (bf16_t)s[jt][2], (bf16_t)s[jt][3] };
      *(bf16x4*)&Ps[(w * 16 + l16) * 136 + jt * 16 + quad * 4] = pk;
    }

    // mid: V(kt) landed (4 oldest of 8 outstanding); Ps writes visible
    asm volatile("s_waitcnt vmcnt(4) lgkmcnt(0)" ::: "memory");
    __builtin_amdgcn_s_barrier();
    SBAR0();

    __builtin_amdgcn_s_setprio(1);
#pragma unroll
    for (int kc = 0; kc < 4; ++kc) {
      bf16x8 bp = *(const bf16x8*)&Ps[(w * 16 + l16) * 136 + kc * 32 + quad * 8];
#pragma unroll
      for (int dt = 0; dt < 4; ++dt) {
        int phys = ((kc * 4 + quad) ^ l16) << 3;
        bf16x8 av = *(const bf16x8*)&Vs[(dt * 16 + l16) * 128 + phys];
        o[dt] = MFMA16(av, bp, o[dt]);
      }
    }
    __builtin_amdgcn_s_setprio(0);
  }

  float inv = 1.0f / l_s;
#pragma unroll
  for (int dt = 0; dt < 4; ++dt) {
    bf16x4 ov = { (bf16_t)(o[dt][0] * inv), (bf16_t)(o[dt][1] * inv),
                  (bf16_t)(o[dt][2] * inv), (bf16_t)(o[dt][3] * inv) };
    *(bf16x4*)&Ps[(w * 16 + l16) * 136 + dt * 16 + quad * 4] = ov;
  }
  __syncthreads();
  {
    int sr = tid >> 2, sc = (tid & 3) << 4;
    int4 r0 = *(const int4*)&Ps[sr * 136 + sc];
    int4 r1 = *(const int4*)&Ps[sr * 136 + sc + 8];
    bf16_t* aout = AO + ((size_t)(b * 2048 + qt * 64 + sr)) * INNER + h * DHEAD + sc;
    *(int4*)aout       = r0;
    *(int4*)(aout + 8) = r1;
  }
}

// ---------- launch ----------
extern "C" void kernel_launch(void* const* d_in, const int* in_sizes, int n_in,
                              void* d_out, int out_size, void* d_ws, size_t ws_size,
                              hipStream_t stream) {
  const float* x   = (const float*)d_in[0];
  const float* ctx = (const float*)d_in[1];
  const float* Wq  = (const float*)d_in[2];
  const float* Wk  = (const float*)d_in[3];
  const float* Wv  = (const float*)d_in[4];
  const float* Wo  = (const float*)d_in[5];
  const float* bo  = (const float*)d_in[6];
  float* out = (float*)d_out;

  char* ws = (char*)d_ws;
  const size_t MB = 1048576;
  bf16_t* WqT = (bf16_t*)(ws + 0 * MB);    //  1 MB  [512][1024]
  bf16_t* WkT = (bf16_t*)(ws + 1 * MB);    //  1 MB
  bf16_t* WvT = (bf16_t*)(ws + 2 * MB);    //  1 MB
  bf16_t* WoT = (bf16_t*)(ws + 3 * MB);    //  1 MB  [1024][512]
  bf16_t* Qb  = (bf16_t*)(ws + 4 * MB);    //  4 MB  [4096][512] (pre-scaled)
  bf16_t* Kb  = (bf16_t*)(ws + 8 * MB);    //  4 MB  [4096][512]
  bf16_t* Vt  = (bf16_t*)(ws + 12 * MB);   //  4 MB  [16][64][2048]
  bf16_t* AO  = (bf16_t*)(ws + 16 * MB);   //  4 MB  [4096][512]

  pre_w_k<<<512, 256, 0, stream>>>(Wq, Wk, Wv, Wo, WqT, WkT, WvT, WoT);
  gemm_qkv_k<<<512, 256, 0, stream>>>(x, ctx, WqT, WkT, WvT, Qb, Kb, Vt);
  attn_k<<<512, 256, 0, stream>>>(Qb, Kb, Vt, AO);
  gemm_out_k<<<512, 256, 0, stream>>>(AO, WoT, bo, out);
}

// Round 14
// 152.768 us; speedup vs baseline: 3.8257x; 1.0403x over previous
//
#include <hip/hip_runtime.h>
#include <math.h>

// ---------- types ----------
typedef __bf16 bf16_t;
typedef __bf16 bf16x8 __attribute__((ext_vector_type(8)));
typedef __bf16 bf16x4 __attribute__((ext_vector_type(4)));
typedef float  f32x4  __attribute__((ext_vector_type(4)));
typedef int    i32x4  __attribute__((ext_vector_type(4)));

#define MFMA16(a, b, c) __builtin_amdgcn_mfma_f32_16x16x32_bf16((a), (b), (c), 0, 0, 0)

// B=2, N=M=2048, QUERY_DIM=CONTEXT_DIM=1024, HEADS=8, DIM_HEAD=64, INNER=512
#define INNER   512
#define DHEAD   64
// SCALE * log2(e): Q pre-scaled so softmax runs in exp2 domain
#define QSCALE  0.18033688f

// direct HBM -> LDS, 16 B per lane; LDS dest = wave-uniform base + lane*16
__device__ __forceinline__ void g2l(const bf16_t* g, bf16_t* l) {
  __builtin_amdgcn_global_load_lds(
      (const __attribute__((address_space(1))) unsigned int*)g,
      (__attribute__((address_space(3))) unsigned int*)l, 16, 0, 0);
}

#define SBAR0() __builtin_amdgcn_sched_barrier(0)

// ---------- weight transpose+convert ----------
__global__ __launch_bounds__(256) void pre_w_k(const float* __restrict__ Wq,
                                               const float* __restrict__ Wk,
                                               const float* __restrict__ Wv,
                                               const float* __restrict__ Wo,
                                               bf16_t* __restrict__ WqT,
                                               bf16_t* __restrict__ WkT,
                                               bf16_t* __restrict__ WvT,
                                               bf16_t* __restrict__ WoT) {
  __shared__ float tile[64][65];
  int t = blockIdx.x;               // 0..511, 4 matrices x 128 tiles
  int z = t >> 7, bid = t & 127;
  const float* W; bf16_t* WT; int K, N;
  if (z == 0)      { W = Wq; WT = WqT; K = 1024; N = 512; }
  else if (z == 1) { W = Wk; WT = WkT; K = 1024; N = 512; }
  else if (z == 2) { W = Wv; WT = WvT; K = 1024; N = 512; }
  else             { W = Wo; WT = WoT; K = 512;  N = 1024; }
  int tK = K >> 6;
  int kt = bid % tK, nt = bid / tK;
  int k0 = kt << 6, n0 = nt << 6;
  for (int idx = threadIdx.x; idx < 4096; idx += 256) {
    int r = idx >> 6, c = idx & 63;
    tile[r][c] = W[(size_t)(k0 + r) * N + n0 + c];
  }
  __syncthreads();
  for (int idx = threadIdx.x; idx < 4096; idx += 256) {
    int r = idx >> 6, c = idx & 63;
    WT[(size_t)(n0 + r) * K + k0 + c] = (bf16_t)tile[c][r];
  }
}

// ---------- qkv GEMM core: (MI*32)x128 tile, BK=64, counted-vmcnt pipeline ----------
// A = fp32 (x/ctx), reg-staged depth-2 (ping-pong pA0/pA1, static indexing);
// B = bf16 W^T via global_load_lds (pre-swizzled source).
// ISSUE ORDER IS THE CORRECTNESS LEDGER (round-11 lesson): B g2l before A loads,
// pinned with sched_barrier(0) at every ledger boundary.
//   top:  vmcnt(2*MI)   = B(kc) landed; A(kc+1) [2*MI newer] stays in flight
//   tail: vmcnt(2*MI+4) = A(kc+1) landed; B(kc+1)+A(kc+2) stay in flight
// K-indices wrap on the tail (dummy loads into dead buffers keep counts uniform).
#define QKV_STEP(kc, CURA, NXTA, CURB, NXTB, PRC, PRF)                           \
  {                                                                              \
    asm volatile("s_waitcnt vmcnt(%c0) lgkmcnt(0)" :: "i"(2 * MI) : "memory");   \
    __builtin_amdgcn_s_barrier();                                                \
    SBAR0();                                                                     \
    {                                                                            \
      const int k0b = (((kc) + 1) & (KT - 1)) * 64;                              \
      _Pragma("unroll")                                                          \
      for (int p = 0; p < 4; ++p)                                                \
        g2l(gb + (size_t)(p * 8) * K + k0b, lB + (NXTB) + p * 512);              \
    }                                                                            \
    SBAR0();   /* pin: B g2l issued before A loads (vmcnt ledger) */             \
    {                                                                            \
      const int k0a = (((kc) + 2) & (KT - 1)) * 64;                              \
      _Pragma("unroll")                                                          \
      for (int p = 0; p < MI; ++p) {                                             \
        const float* s_ = ga + (size_t)(p * 8) * K + k0a;                        \
        PRF[2 * p]     = *(const f32x4*)s_;                                      \
        PRF[2 * p + 1] = *(const f32x4*)(s_ + 4);                                \
      }                                                                          \
    }                                                                            \
    SBAR0();   /* pin: A loads issued before MFMA cluster */                     \
    _Pragma("unroll")                                                            \
    for (int ks = 0; ks < 2; ++ks) {                                             \
      const int phys = ((ks * 4 + quad) ^ (l16 & 7)) << 3;                       \
      bf16x8 af[MI], bfr[4];                                                     \
      _Pragma("unroll")                                                          \
      for (int i = 0; i < MI; ++i)                                               \
        af[i] = *(const bf16x8*)&As[(CURA) + (mrow + i * 16 + l16) * 64 + phys]; \
      _Pragma("unroll")                                                          \
      for (int j = 0; j < 4; ++j)                                                \
        bfr[j] = *(const bf16x8*)&Bs[(CURB) + (ncol + j * 16 + l16) * 64 + phys];\
      _Pragma("unroll")                                                          \
      for (int i = 0; i < MI; ++i)                                               \
        _Pragma("unroll")                                                        \
        for (int j = 0; j < 4; ++j)                                              \
          acc[i][j] = MFMA16(af[i], bfr[j], acc[i][j]);                          \
    }                                                                            \
    asm volatile("s_waitcnt vmcnt(%c0)" :: "i"(2 * MI + 4) : "memory");          \
    SBAR0();                                                                     \
    _Pragma("unroll")                                                            \
    for (int p = 0; p < MI; ++p) {                                               \
      bf16x8 h_;                                                                 \
      _Pragma("unroll")                                                          \
      for (int e = 0; e < 4; ++e) {                                              \
        h_[e]     = (bf16_t)PRC[2 * p][e];                                       \
        h_[4 + e] = (bf16_t)PRC[2 * p + 1][e];                                   \
      }                                                                          \
      *(bf16x8*)&lA[(NXTA) + p * 512 + lane * 8] = h_;                           \
    }                                                                            \
  }

// sm: shared 64 KB block (As = first 2*BM*64 elems, Bs = next 2*128*64).
template<int MI>
__device__ __forceinline__ void gemm_qkv_core(bf16_t* sm,
                                              const float* __restrict__ A,
                                              const bf16_t* __restrict__ Bt,
                                              int row0, int n0,
                                              int mode, float scale,
                                              bf16_t* __restrict__ Cb) {
  constexpr int K = 1024, KT = 16;
  constexpr int ABUF = MI * 2048;       // per-buffer A elems (BM*64)
  bf16_t* As = sm;                      // 2*ABUF
  bf16_t* Bs = sm + 2 * ABUF;           // 2*8192
  const int tid = threadIdx.x;
  const int w = tid >> 6, lane = tid & 63, quad = lane >> 4, l16 = lane & 15;
  const int sr8  = lane >> 3;
  const int slog = ((lane & 7) ^ sr8) << 3;
  const float*  ga = A  + (size_t)(row0 + w * (MI * 8) + sr8) * K + slog;
  const bf16_t* gb = Bt + (size_t)(n0   + w * 32 + sr8) * K + slog;
  bf16_t* lA = As + w * MI * 512;
  bf16_t* lB = Bs + w * 2048;

  f32x4 acc[MI][4];
#pragma unroll
  for (int i = 0; i < MI; ++i)
#pragma unroll
    for (int j = 0; j < 4; ++j) acc[i][j] = f32x4{0.f, 0.f, 0.f, 0.f};

  f32x4 pA0[2 * MI], pA1[2 * MI];       // ping-pong A prefetch (static names)
  const int mrow = (w & 1) * (MI * 16), ncol = (w >> 1) << 6;

  // prologue: A(0) direct cvt -> As[0] (loads fully consumed before ds_write);
  // B(0) g2l; A(1) -> pA0.
#pragma unroll
  for (int p = 0; p < MI; ++p) {
    const float* s = ga + (size_t)(p * 8) * K;
    f32x4 f0 = *(const f32x4*)s;
    f32x4 f1 = *(const f32x4*)(s + 4);
    bf16x8 h;
#pragma unroll
    for (int e = 0; e < 4; ++e) { h[e] = (bf16_t)f0[e]; h[4 + e] = (bf16_t)f1[e]; }
    *(bf16x8*)&lA[p * 512 + lane * 8] = h;
  }
  SBAR0();
#pragma unroll
  for (int p = 0; p < 4; ++p)
    g2l(gb + (size_t)(p * 8) * K, lB + p * 512);
  SBAR0();   // pin: B(0) g2l issued before A(1) loads (vmcnt ledger)
#pragma unroll
  for (int p = 0; p < MI; ++p) {
    const float* s = ga + (size_t)(p * 8) * K + 64;
    pA0[2 * p]     = *(const f32x4*)s;
    pA0[2 * p + 1] = *(const f32x4*)(s + 4);
  }
  SBAR0();

  for (int kc = 0; kc < KT; kc += 2) {
    QKV_STEP(kc,     0,    ABUF, 0,    8192, pA0, pA1);
    QKV_STEP(kc + 1, ABUF, 0,    8192, 0,    pA1, pA0);
  }

  // epilogue: C/D layout col=l16, row=quad*4+reg
#pragma unroll
  for (int i = 0; i < MI; ++i) {
    int row = row0 + mrow + i * 16 + quad * 4;
#pragma unroll
    for (int j = 0; j < 4; ++j) {
      int col = n0 + ncol + j * 16 + l16;
      if (mode == 2) {
        // scatter to Vt[bh=b*8+h][d][key]: row -> (b,key), col -> (h,d)
        int bb = row >> 11, key = row & 2047;
        int hh = col >> 6,  d   = col & 63;
        bf16x4 v = { (bf16_t)acc[i][j][0], (bf16_t)acc[i][j][1],
                     (bf16_t)acc[i][j][2], (bf16_t)acc[i][j][3] };
        *(bf16x4*)&Cb[((size_t)((bb * 8 + hh) * 64 + d)) * 2048 + key] = v;
      } else {
#pragma unroll
        for (int r = 0; r < 4; ++r)
          Cb[(size_t)(row + r) * 512 + col] = (bf16_t)(acc[i][j][r] * scale);
      }
    }
  }
}

// ---------- QKV: 1-D grid 512 (Q 128 + K 128 @BM=128, V 256 @BM=64) ----------
__global__ __launch_bounds__(256, 2) void gemm_qkv_k(const float* __restrict__ x,
                                                     const float* __restrict__ ctx,
                                                     const bf16_t* __restrict__ WqT,
                                                     const bf16_t* __restrict__ WkT,
                                                     const bf16_t* __restrict__ WvT,
                                                     bf16_t* __restrict__ Qb,
                                                     bf16_t* __restrict__ Kb,
                                                     bf16_t* __restrict__ Vt) {
  __shared__ __align__(16) bf16_t smem[32768];   // 64 KB shared by both paths
  int bid = blockIdx.x;             // 0..511
  if (bid < 256) {                  // Q (0..127) / K (128..255), BM=128
    int z = bid >> 7;
    int t = bid & 127;
    int xcd = t & 7, slot = t >> 3;            // slot 0..15
    int m = (xcd << 2) | (slot >> 2);          // XCD owns m in [4x, 4x+4)
    int n = slot & 3;
    const float* A   = (z == 0) ? x   : ctx;
    const bf16_t* Bt = (z == 0) ? WqT : WkT;
    bf16_t* C        = (z == 0) ? Qb  : Kb;
    float scale      = (z == 0) ? QSCALE : 1.0f;
    gemm_qkv_core<4>(smem, A, Bt, m * 128, n * 128, 0, scale, C);
  } else {                          // V, BM=64, 256 blocks
    int t = bid - 256;              // 0..255
    int xcd = t & 7, slot = t >> 3;            // slot 0..31
    int m = (xcd << 3) | (slot >> 2);          // XCD owns m in [8x, 8x+8)
    int n = slot & 3;
    gemm_qkv_core<2>(smem, ctx, WvT, m * 64, n * 128, 2, 1.0f, Vt);
  }
}

// ---------- out-proj core: 64x128 tile, K=512, 3-buffer counted-vmcnt ----------
__device__ __forceinline__ void gemm_out_core(const bf16_t* __restrict__ Ab,
                                              const bf16_t* __restrict__ Bt,
                                              int row0, int n0,
                                              float* __restrict__ Cf,
                                              const float* __restrict__ bias) {
  constexpr int K = 512, KT = 8;
  __shared__ bf16_t As[3 * 4096];   // 3 bufs x 64x64  (24 KB)
  __shared__ bf16_t Bs[3 * 8192];   // 3 bufs x 128x64 (48 KB)
  const int tid = threadIdx.x;
  const int w = tid >> 6, lane = tid & 63, quad = lane >> 4, l16 = lane & 15;
  const int sr8  = lane >> 3;
  const int slog = ((lane & 7) ^ sr8) << 3;
  const bf16_t* ga = Ab + (size_t)(row0 + w * 16 + sr8) * K + slog;
  const bf16_t* gb = Bt + (size_t)(n0   + w * 32 + sr8) * K + slog;
  bf16_t* lA = As + w * 1024;       // + buf*4096 + p*512
  bf16_t* lB = Bs + w * 2048;       // + buf*8192 + p*512

  f32x4 acc[2][4];
#pragma unroll
  for (int i = 0; i < 2; ++i)
#pragma unroll
    for (int j = 0; j < 4; ++j) acc[i][j] = f32x4{0.f, 0.f, 0.f, 0.f};

  const int mrow = (w & 1) * 32, ncol = (w >> 1) << 6;

  // prologue: issue T0 then T1 (A-then-B within each tile, all pinned)
#pragma unroll
  for (int t = 0; t < 2; ++t) {
#pragma unroll
    for (int p = 0; p < 2; ++p)
      g2l(ga + (size_t)(p * 8) * K + t * 64, lA + t * 4096 + p * 512);
    SBAR0();
#pragma unroll
    for (int p = 0; p < 4; ++p)
      g2l(gb + (size_t)(p * 8) * K + t * 64, lB + t * 8192 + p * 512);
    SBAR0();
  }

  int rbuf = 0;                     // = kc % 3
  int wbuf = 2;                     // = (kc+2) % 3
  for (int kc = 0; kc < KT; ++kc) {
    asm volatile("s_waitcnt vmcnt(6) lgkmcnt(0)" ::: "memory");  // T(kc) landed
    __builtin_amdgcn_s_barrier();
    SBAR0();
    {
      const int kn = ((kc + 2) & (KT - 1)) * 64;  // wrap: dummy into dead buffer
#pragma unroll
      for (int p = 0; p < 2; ++p)
        g2l(ga + (size_t)(p * 8) * K + kn, lA + wbuf * 4096 + p * 512);
      SBAR0();   // pin: A before B (tile-granular vmcnt ledger)
#pragma unroll
      for (int p = 0; p < 4; ++p)
        g2l(gb + (size_t)(p * 8) * K + kn, lB + wbuf * 8192 + p * 512);
      SBAR0();
    }
    const int cA = rbuf * 4096, cB = rbuf * 8192;
#pragma unroll
    for (int ks = 0; ks < 2; ++ks) {
      const int phys = ((ks * 4 + quad) ^ (l16 & 7)) << 3;
      bf16x8 af[2], bfr[4];
#pragma unroll
      for (int i = 0; i < 2; ++i)
        af[i] = *(const bf16x8*)&As[cA + (mrow + i * 16 + l16) * 64 + phys];
#pragma unroll
      for (int j = 0; j < 4; ++j)
        bfr[j] = *(const bf16x8*)&Bs[cB + (ncol + j * 16 + l16) * 64 + phys];
#pragma unroll
      for (int i = 0; i < 2; ++i)
#pragma unroll
        for (int j = 0; j < 4; ++j)
          acc[i][j] = MFMA16(af[i], bfr[j], acc[i][j]);
    }
    rbuf = (rbuf == 2) ? 0 : rbuf + 1;
    wbuf = (wbuf == 2) ? 0 : wbuf + 1;
  }

#pragma unroll
  for (int i = 0; i < 2; ++i) {
    int row = row0 + mrow + i * 16 + quad * 4;
#pragma unroll
    for (int j = 0; j < 4; ++j) {
      int col = n0 + ncol + j * 16 + l16;
#pragma unroll
      for (int r = 0; r < 4; ++r)
        Cf[(size_t)(row + r) * 1024 + col] = acc[i][j][r] + bias[col];
    }
  }
}

// ---------- out-proj: 1-D grid 512, XCD-aware m-grouping ----------
__global__ __launch_bounds__(256, 2) void gemm_out_k(const bf16_t* __restrict__ AO,
                                                     const bf16_t* __restrict__ WoT,
                                                     const float* __restrict__ bo,
                                                     float* __restrict__ out) {
  int bid = blockIdx.x;             // 0..511
  int xcd  = bid & 7;
  int slot = bid >> 3;              // 0..63
  int m = (xcd << 3) | (slot >> 3); // 0..63
  int n = slot & 7;
  gemm_out_core(AO, WoT, m * 64, n * 128, out, bo);
}

// ---------- flash attention: 49.4 KB LDS -> 3 blocks/CU (round-14) ----------
// Counter evidence (r13): attn = 44us, MfmaUtil 15%, VALUBusy 30%, Occ 19% ->
// latency-bound at 2 blocks/CU (66.5 KB LDS). Fix: single-buffer Ks (16 KB) with
// T14 reg-staged K-prefetch: K(kt+1) -> 4x16B regs at top (HBM latency hides
// under QK+softmax), ds_write -> Ks after mid barrier (all QK reads done; PV
// doesn't touch Ks). Ledger simplifies: only V's 4 g2l outstanding at mid
// (vmcnt(4), V-before-K pinned); K-reg dep is compiler-tracked (auto-wait
// before ds_write, free by then). Same swizzle (pre-swizzled global source,
// linear chunk lane&7 dest).
__global__ __launch_bounds__(256, 3) void attn_k(const bf16_t* __restrict__ Qb,
                                                 const bf16_t* __restrict__ Kb,
                                                 const bf16_t* __restrict__ Vt,
                                                 bf16_t* __restrict__ AO) {
  const int tid = threadIdx.x;
  const int w = tid >> 6, lane = tid & 63, quad = lane >> 4, l16 = lane & 15;
  int bid = blockIdx.x;             // 0..511
  int xcd  = bid & 7;
  int slot = bid >> 3;              // 0..63
  const int qt = slot & 31;         // 0..31
  const int bh = (xcd << 1) | (slot >> 5);   // 0..15
  const int b = bh >> 3, h = bh & 7;

  __shared__ bf16_t Ks[128 * 64];      // 16 KB single buffer, swizzle r&7
  __shared__ bf16_t Vs[64 * 128];      // 16 KB [d][key], swizzle r&15
  __shared__ bf16_t Ps[64 * 136];      // 17.4 KB padded, wave-private rows

  const int qrow = b * 2048 + qt * 64 + w * 16 + l16;
  const bf16_t* qptr = Qb + (size_t)qrow * INNER + h * DHEAD;
  bf16x8 bq[2];
  bq[0] = *(const bf16x8*)(qptr + quad * 8);
  bq[1] = *(const bf16x8*)(qptr + 32 + quad * 8);

  f32x4 o[4];
#pragma unroll
  for (int dt = 0; dt < 4; ++dt) o[dt] = f32x4{0.f, 0.f, 0.f, 0.f};
  float m_s = -__builtin_inff(), l_s = 0.f;

  const bf16_t* kbase  = Kb + ((size_t)b * 2048) * INNER + h * DHEAD;
  const bf16_t* vtbase = Vt + ((size_t)bh * 64) * 2048;

  const int krow = lane >> 3;
  const int kcol = ((lane & 7) ^ (lane >> 3)) << 3;
  const int vrow = lane >> 4;
  const int kldsoff = w * 2048 + lane * 8;   // elem offset for K ds_write (p adds 512)

  // prologue: K(0) -> Ks via g2l (drained by first __syncthreads)
#pragma unroll
  for (int p = 0; p < 4; ++p)
    g2l(kbase + (size_t)(w * 32 + p * 8 + krow) * INNER + kcol,
        &Ks[w * 2048 + p * 512]);

  i32x4 kp0, kp1, kp2, kp3;           // K(kt+1) reg prefetch (static names)

  for (int kt = 0; kt < 16; ++kt) {
    __syncthreads();                 // top: Ks (ds_writes) + Vs free; vm drained
    // V(kt) g2l first (waited at mid), K(kt+1) reg-loads second (pinned).
#pragma unroll
    for (int p = 0; p < 4; ++p) {
      int vlog = ((lane & 15) ^ ((p * 4 + vrow) & 15)) << 3;
      g2l(vtbase + (size_t)(w * 16 + p * 4 + vrow) * 2048 + kt * 128 + vlog,
          &Vs[w * 2048 + p * 512]);
    }
    SBAR0();   // pin: V g2l issued before K reg-loads (vmcnt ledger)
    {
      const int ktn = (kt + 1) & 15;  // wrap: kt=15 loads dead data
      const bf16_t* ksrc = kbase + (size_t)(ktn * 128 + w * 32 + krow) * INNER + kcol;
      kp0 = *(const i32x4*)(ksrc);
      kp1 = *(const i32x4*)(ksrc + (size_t)8  * INNER);
      kp2 = *(const i32x4*)(ksrc + (size_t)16 * INNER);
      kp3 = *(const i32x4*)(ksrc + (size_t)24 * INNER);
    }
    SBAR0();

    f32x4 s[8];
#pragma unroll
    for (int jt = 0; jt < 8; ++jt) s[jt] = f32x4{0.f, 0.f, 0.f, 0.f};
    __builtin_amdgcn_s_setprio(1);      // T5: favor MFMA wave on CU scheduler
#pragma unroll
    for (int jt = 0; jt < 8; ++jt) {
#pragma unroll
      for (int ks = 0; ks < 2; ++ks) {
        int phys = ((ks * 4 + quad) ^ (l16 & 7)) << 3;
        bf16x8 ak = *(const bf16x8*)&Ks[(jt * 16 + l16) * 64 + phys];
        s[jt] = MFMA16(ak, bq[ks], s[jt]);
      }
    }
    __builtin_amdgcn_s_setprio(0);

    float mx = -__builtin_inff();
#pragma unroll
    for (int jt = 0; jt < 8; ++jt) {
      float a = fmaxf(fmaxf(s[jt][0], s[jt][1]), fmaxf(s[jt][2], s[jt][3]));
      mx = fmaxf(mx, a);
    }
    mx = fmaxf(mx, __shfl_xor(mx, 16, 64));
    mx = fmaxf(mx, __shfl_xor(mx, 32, 64));
    // defer-max: only rescale when some row's max grew by > 8 (exp2 units).
    if (!__all(mx - m_s <= 8.0f)) {
      float mnew = fmaxf(m_s, mx);
      float alpha = __builtin_amdgcn_exp2f(m_s - mnew);
      l_s *= alpha;
#pragma unroll
      for (int dt = 0; dt < 4; ++dt) o[dt] *= alpha;
      m_s = mnew;
    }
    float rs = 0.f;
#pragma unroll
    for (int jt = 0; jt < 8; ++jt) {
#pragma unroll
      for (int r = 0; r < 4; ++r) {
        float p = __builtin_amdgcn_exp2f(s[jt][r] - m_s);
        s[jt][r] = p;
        rs += p;
      }
    }
    rs += __shfl_xor(rs, 16, 64);
    rs += __shfl_xor(rs, 32, 64);
    l_s += rs;

#pragma unroll
    for (int jt = 0; jt < 8; ++jt) {
      bf16x4 pk = { (bf16_t)s[jt][0], (bf16_t)s[jt][1],
                    (bf16_t)s[jt][2], (bf16_t)s[jt][3] };
      *(bf16x4*)&Ps[(w * 16 + l16) * 136 + jt * 16 + quad * 4] = pk;
    }

    // mid: V(kt) landed (4 oldest; K regs are the 4 newest, still in flight);
    // Ps writes visible. All waves' QK reads of Ks complete past this barrier.
    asm volatile("s_waitcnt vmcnt(4) lgkmcnt(0)" ::: "memory");
    __builtin_amdgcn_s_barrier();
    SBAR0();

    // K(kt+1) regs -> Ks (compiler auto-waits the reg deps; loads issued ~600
    // cycles ago -> free). Overlaps PV, which reads only Vs/Ps.
    *(i32x4*)&Ks[kldsoff]        = kp0;
    *(i32x4*)&Ks[kldsoff + 512]  = kp1;
    *(i32x4*)&Ks[kldsoff + 1024] = kp2;
    *(i32x4*)&Ks[kldsoff + 1536] = kp3;

    __builtin_amdgcn_s_setprio(1);
#pragma unroll
    for (int kc = 0; kc < 4; ++kc) {
      bf16x8 bp = *(const bf16x8*)&Ps[(w * 16 + l16) * 136 + kc * 32 + quad * 8];
#pragma unroll
      for (int dt = 0; dt < 4; ++dt) {
        int phys = ((kc * 4 + quad) ^ l16) << 3;
        bf16x8 av = *(const bf16x8*)&Vs[(dt * 16 + l16) * 128 + phys];
        o[dt] = MFMA16(av, bp, o[dt]);
      }
    }
    __builtin_amdgcn_s_setprio(0);
  }

  float inv = 1.0f / l_s;
#pragma unroll
  for (int dt = 0; dt < 4; ++dt) {
    bf16x4 ov = { (bf16_t)(o[dt][0] * inv), (bf16_t)(o[dt][1] * inv),
                  (bf16_t)(o[dt][2] * inv), (bf16_t)(o[dt][3] * inv) };
    *(bf16x4*)&Ps[(w * 16 + l16) * 136 + dt * 16 + quad * 4] = ov;
  }
  __syncthreads();
  {
    int sr = tid >> 2, sc = (tid & 3) << 4;
    int4 r0 = *(const int4*)&Ps[sr * 136 + sc];
    int4 r1 = *(const int4*)&Ps[sr * 136 + sc + 8];
    bf16_t* aout = AO + ((size_t)(b * 2048 + qt * 64 + sr)) * INNER + h * DHEAD + sc;
    *(int4*)aout       = r0;
    *(int4*)(aout + 8) = r1;
  }
}

// ---------- launch ----------
extern "C" void kernel_launch(void* const* d_in, const int* in_sizes, int n_in,
                              void* d_out, int out_size, void* d_ws, size_t ws_size,
                              hipStream_t stream) {
  const float* x   = (const float*)d_in[0];
  const float* ctx = (const float*)d_in[1];
  const float* Wq  = (const float*)d_in[2];
  const float* Wk  = (const float*)d_in[3];
  const float* Wv  = (const float*)d_in[4];
  const float* Wo  = (const float*)d_in[5];
  const float* bo  = (const float*)d_in[6];
  float* out = (float*)d_out;

  char* ws = (char*)d_ws;
  const size_t MB = 1048576;
  bf16_t* WqT = (bf16_t*)(ws + 0 * MB);    //  1 MB  [512][1024]
  bf16_t* WkT = (bf16_t*)(ws + 1 * MB);    //  1 MB
  bf16_t* WvT = (bf16_t*)(ws + 2 * MB);    //  1 MB
  bf16_t* WoT = (bf16_t*)(ws + 3 * MB);    //  1 MB  [1024][512]
  bf16_t* Qb  = (bf16_t*)(ws + 4 * MB);    //  4 MB  [4096][512] (pre-scaled)
  bf16_t* Kb  = (bf16_t*)(ws + 8 * MB);    //  4 MB  [4096][512]
  bf16_t* Vt  = (bf16_t*)(ws + 12 * MB);   //  4 MB  [16][64][2048]
  bf16_t* AO  = (bf16_t*)(ws + 16 * MB);   //  4 MB  [4096][512]

  pre_w_k<<<512, 256, 0, stream>>>(Wq, Wk, Wv, Wo, WqT, WkT, WvT, WoT);
  gemm_qkv_k<<<512, 256, 0, stream>>>(x, ctx, WqT, WkT, WvT, Qb, Kb, Vt);
  attn_k<<<512, 256, 0, stream>>>(Qb, Kb, Vt, AO);
  gemm_out_k<<<512, 256, 0, stream>>>(AO, WoT, bo, out);
}